// Round 1
// baseline (713.777 us; speedup 1.0000x reference)
//
#include <hip/hip_runtime.h>

// ---------------------------------------------------------------------------
// Problem constants: B=8, N=4096 (64x64 image), DIM=768, HEADS=12, HEAD_DIM=64
// EXP=2 -> EDIM=1536, expanded heads = 24.
// ---------------------------------------------------------------------------
#define NB 8
#define NTOK 4096
#define CDIM 768
#define EDIM 1536
#define NHEADS 12
#define HD 64
#define TOTTOK (NB * NTOK)          // 32768

typedef float floatx4 __attribute__((ext_vector_type(4)));
typedef __bf16 bf16x8 __attribute__((ext_vector_type(8)));

// async 16B global -> LDS (lane-contiguous LDS dest: wave base + lane*16)
__device__ __forceinline__ void gld16(const __bf16* g, void* l) {
  __builtin_amdgcn_global_load_lds(
      (const __attribute__((address_space(1))) unsigned int*)g,
      (__attribute__((address_space(3))) unsigned int*)l, 16, 0, 0);
}

#define MFMA16(a, b, c) __builtin_amdgcn_mfma_f32_16x16x32_bf16(a, b, c, 0, 0, 0)
#define FENCE() asm volatile("" ::: "memory")
#define BARRIER() do { FENCE(); __builtin_amdgcn_s_barrier(); FENCE(); } while (0)

// ---------------------------------------------------------------------------
// fp32 -> bf16 elementwise convert (x)
// ---------------------------------------------------------------------------
__global__ __launch_bounds__(256) void f32_to_bf16_kernel(
    const float* __restrict__ in, __bf16* __restrict__ out, long n) {
  long i = ((long)blockIdx.x * 256 + threadIdx.x) * 4;
  if (i >= n) return;
  float4 f = *(const float4*)(in + i);
  alignas(8) __bf16 h[4];
  h[0] = (__bf16)f.x; h[1] = (__bf16)f.y; h[2] = (__bf16)f.z; h[3] = (__bf16)f.w;
  *(unsigned long long*)(out + i) = *(const unsigned long long*)h;
}

// ---------------------------------------------------------------------------
// W (K x N fp32, row-major) -> Wt (N x K bf16, row-major)
// grid: (N/32, K/32), block 256
// ---------------------------------------------------------------------------
__global__ __launch_bounds__(256) void transpose_w_kernel(
    const float* __restrict__ W, __bf16* __restrict__ Wt, int K, int N) {
  __shared__ float tile[32][33];
  int nb = blockIdx.x * 32, kb = blockIdx.y * 32;
  int tx = threadIdx.x & 31, ty = threadIdx.x >> 5;  // ty 0..7
  #pragma unroll
  for (int i = ty; i < 32; i += 8)
    tile[i][tx] = W[(long)(kb + i) * N + nb + tx];
  __syncthreads();
  #pragma unroll
  for (int i = ty; i < 32; i += 8)
    Wt[(long)(nb + i) * K + kb + tx] = (__bf16)tile[tx][i];
}

// ---------------------------------------------------------------------------
// 256x256 8-phase bf16 MFMA GEMM (T2+T3+T4+T5 structure).
// C(MxN) = A(MxK) @ Bt(NxK)^T. BK=64, 512 threads = 8 waves (2M x 4N),
// per-wave output 128x64 (acc[8][4] 16x16 frags), LDS 128 KiB (2-deep dbuf).
//
// Staging: per K-tile, 8 "slices" of 64 rows x 64 cols (A0..A3, B0..B3);
// each slice = 1 global_load_lds_dwordx4 per wave (wave covers 8 rows).
// LDS dest is linear (HW: wave base + lane*16); the chunk XOR swizzle
// (stored chunk s at row r holds logical chunk s^(r&7)) is applied by
// pre-swizzling the per-lane GLOBAL source (rule #21: both-sides swizzle).
// ds_read_b128 frag reads then hit 8 distinct banksets (2-way = free).
//
// Schedule (per K-tile t, computing buf[t&1], staging tile t+1 -> buf[~t&1]):
//   ph1: read af_lo+bf01 | stage B0,B1(t+1)            | bar,lgkm0,16 MFMA,bar
//   ph2: read bf23       | stage B2,B3(t+1), vmcnt(4)  | bar,lgkm0,16 MFMA,bar
//   ph3: read af_hi      | stage A0,A2(t+1)            | bar,lgkm0,16 MFMA,bar
//   ph4: read bf01       | stage A1,A3(t+1), vmcnt(2)  | bar,lgkm0,16 MFMA,bar
// Ledger: entering tile t, only A1,A3(t) in flight (2). ph2's vmcnt(4)
// retires them before ph3 reads odd A-slabs. ph4's vmcnt(2) retires
// B0-3 + A0,A2 of t+1 (needed at t+1 ph1/ph2), leaving A1,A3(t+1) -> invariant.
// Staging into buf[~t&1] is safe: its last reads (tile t-1) completed at
// tile t-1 ph4's post-MFMA barrier (every wave did lgkmcnt(0) before it).
// vmcnt never drains to 0 in the main loop (T4); final tile uses vmcnt(0).
//
// Block swizzle: flat&7 = XCD owns a contiguous y-strip; requires
// (M/256)%8==0 (M=32768 -> 128 y-tiles, 16/XCD).
// mode 0: split bf16 epilogue (cols<768 -> C0 stride 768; else C1 stride 1536)
// mode 1: fp32 + bias epilogue into C0 stride N.
// ---------------------------------------------------------------------------
__global__ __launch_bounds__(512, 2) void gemm256_kernel(
    const __bf16* __restrict__ A, const __bf16* __restrict__ Bt,
    void* __restrict__ C0, void* __restrict__ C1,
    const float* __restrict__ bias,
    int M, int N, int K, int nxb, int mode) {
  __shared__ __bf16 As[2][256 * 64];   // 64 KB
  __shared__ __bf16 Bs[2][256 * 64];   // 64 KB
  const int tid = threadIdx.x;
  const int wave = tid >> 6, lane = tid & 63;

  const int flat = blockIdx.x;
  const int xcd = flat & 7, rem = flat >> 3;
  const int per = (M >> 8) >> 3;           // y-tiles per XCD
  const int yb = xcd * per + rem / nxb;
  const int xb = rem % nxb;
  const long m0 = (long)yb * 256;
  const int n0 = xb * 256;

  const int wm = (wave >> 2) * 128;        // M-half of this wave
  const int wn = (wave & 3) * 64;          // N-quarter of this wave

  // staging: wave covers rows [wave*8, wave*8+8) of each 64-row slice.
  // lane l -> row wave*8 + (l>>3), stored chunk l&7; fetch global chunk
  // (l&7)^(row&7) so swizzled reads see logical data.
  const int srow = lane >> 3;              // 0..7
  const int gchunk = (lane & 7) ^ srow;    // (row&7)==srow for slice bases %64
  const __bf16* Ag = A + (m0 + wave * 8 + srow) * (long)K + gchunk * 8;
  const __bf16* Bg = Bt + ((long)n0 + wave * 8 + srow) * (long)K + gchunk * 8;
  const long slabK = 64 * (long)K;         // global elems between slices

  const int fr = lane & 15, qh = lane >> 4;
  const int c0 = ((qh ^ (fr & 7)) << 3);        // stored-chunk offset, kk=0
  const int c1 = (((qh + 4) ^ (fr & 7)) << 3);  // stored-chunk offset, kk=1

  floatx4 acc[8][4] = {};
  bf16x8 afl[4][2], bfr[2][2];
  const int nt = K >> 6;

  // prologue: stage tile 0 in order B0 B1 B2 B3 A0 A2 A1 A3
  {
    char* al = (char*)&As[0][0] + wave * 1024;
    char* bl = (char*)&Bs[0][0] + wave * 1024;
    gld16(Bg + 0 * slabK, bl + 0 * 8192);
    gld16(Bg + 1 * slabK, bl + 1 * 8192);
    gld16(Bg + 2 * slabK, bl + 2 * 8192);
    gld16(Bg + 3 * slabK, bl + 3 * 8192);
    gld16(Ag + 0 * slabK, al + 0 * 8192);
    gld16(Ag + 2 * slabK, al + 2 * 8192);
    gld16(Ag + 1 * slabK, al + 1 * 8192);
    gld16(Ag + 3 * slabK, al + 3 * 8192);
  }
  asm volatile("s_waitcnt vmcnt(2)" ::: "memory");  // A1,A3 may stay in flight
  BARRIER();

  for (int t = 0; t < nt; ++t) {
    const int cur = t & 1;
    const bool pf = (t + 1 < nt);
    const __bf16* Ac = &As[cur][0];
    const __bf16* Bc = &Bs[cur][0];
    const __bf16* an = Ag + (t + 1) * 64;
    const __bf16* bn = Bg + (t + 1) * 64;
    char* al = (char*)&As[cur ^ 1][0] + wave * 1024;
    char* bl = (char*)&Bs[cur ^ 1][0] + wave * 1024;

    // ---- phase 1: (m-lo x n01) -------------------------------------------
    #pragma unroll
    for (int i = 0; i < 4; ++i) {
      const __bf16* p = &Ac[(wm + i * 16 + fr) * 64];
      afl[i][0] = *(const bf16x8*)(p + c0);
      afl[i][1] = *(const bf16x8*)(p + c1);
    }
    #pragma unroll
    for (int j = 0; j < 2; ++j) {
      const __bf16* p = &Bc[(wn + j * 16 + fr) * 64];
      bfr[j][0] = *(const bf16x8*)(p + c0);
      bfr[j][1] = *(const bf16x8*)(p + c1);
    }
    if (pf) { gld16(bn, bl); gld16(bn + slabK, bl + 8192); }
    BARRIER();
    asm volatile("s_waitcnt lgkmcnt(0)");
    __builtin_amdgcn_sched_barrier(0);
    __builtin_amdgcn_s_setprio(1);
    #pragma unroll
    for (int i = 0; i < 4; ++i)
      #pragma unroll
      for (int j = 0; j < 2; ++j) {
        acc[i][j] = MFMA16(afl[i][0], bfr[j][0], acc[i][j]);
        acc[i][j] = MFMA16(afl[i][1], bfr[j][1], acc[i][j]);
      }
    __builtin_amdgcn_s_setprio(0);
    BARRIER();

    // ---- phase 2: (m-lo x n23) -------------------------------------------
    #pragma unroll
    for (int j = 0; j < 2; ++j) {
      const __bf16* p = &Bc[(wn + (2 + j) * 16 + fr) * 64];
      bfr[j][0] = *(const bf16x8*)(p + c0);
      bfr[j][1] = *(const bf16x8*)(p + c1);
    }
    if (pf) {
      gld16(bn + 2 * slabK, bl + 2 * 8192);
      gld16(bn + 3 * slabK, bl + 3 * 8192);
      asm volatile("s_waitcnt vmcnt(4)" ::: "memory");  // retire A1,A3(t)
    } else {
      asm volatile("s_waitcnt vmcnt(0)" ::: "memory");  // last tile: drain
    }
    BARRIER();
    asm volatile("s_waitcnt lgkmcnt(0)");
    __builtin_amdgcn_sched_barrier(0);
    __builtin_amdgcn_s_setprio(1);
    #pragma unroll
    for (int i = 0; i < 4; ++i)
      #pragma unroll
      for (int j = 0; j < 2; ++j) {
        acc[i][2 + j] = MFMA16(afl[i][0], bfr[j][0], acc[i][2 + j]);
        acc[i][2 + j] = MFMA16(afl[i][1], bfr[j][1], acc[i][2 + j]);
      }
    __builtin_amdgcn_s_setprio(0);
    BARRIER();

    // ---- phase 3: (m-hi x n23), bf23 still live --------------------------
    #pragma unroll
    for (int i = 0; i < 4; ++i) {
      const __bf16* p = &Ac[(wm + (4 + i) * 16 + fr) * 64];
      afl[i][0] = *(const bf16x8*)(p + c0);
      afl[i][1] = *(const bf16x8*)(p + c1);
    }
    if (pf) { gld16(an, al); gld16(an + 2 * slabK, al + 2 * 8192); }
    BARRIER();
    asm volatile("s_waitcnt lgkmcnt(0)");
    __builtin_amdgcn_sched_barrier(0);
    __builtin_amdgcn_s_setprio(1);
    #pragma unroll
    for (int i = 0; i < 4; ++i)
      #pragma unroll
      for (int j = 0; j < 2; ++j) {
        acc[4 + i][2 + j] = MFMA16(afl[i][0], bfr[j][0], acc[4 + i][2 + j]);
        acc[4 + i][2 + j] = MFMA16(afl[i][1], bfr[j][1], acc[4 + i][2 + j]);
      }
    __builtin_amdgcn_s_setprio(0);
    BARRIER();

    // ---- phase 4: (m-hi x n01), reload bf01 ------------------------------
    #pragma unroll
    for (int j = 0; j < 2; ++j) {
      const __bf16* p = &Bc[(wn + j * 16 + fr) * 64];
      bfr[j][0] = *(const bf16x8*)(p + c0);
      bfr[j][1] = *(const bf16x8*)(p + c1);
    }
    if (pf) {
      gld16(an + slabK, al + 8192);
      gld16(an + 3 * slabK, al + 3 * 8192);
      asm volatile("s_waitcnt vmcnt(2)" ::: "memory");  // B0-3,A0,A2(t+1) landed
    }
    BARRIER();
    asm volatile("s_waitcnt lgkmcnt(0)");
    __builtin_amdgcn_sched_barrier(0);
    __builtin_amdgcn_s_setprio(1);
    #pragma unroll
    for (int i = 0; i < 4; ++i)
      #pragma unroll
      for (int j = 0; j < 2; ++j) {
        acc[4 + i][j] = MFMA16(afl[i][0], bfr[j][0], acc[4 + i][j]);
        acc[4 + i][j] = MFMA16(afl[i][1], bfr[j][1], acc[4 + i][j]);
      }
    __builtin_amdgcn_s_setprio(0);
    BARRIER();
  }

  // epilogue
  const int col = lane & 15, rq = (lane >> 4) * 4;
  if (mode == 1) {
    #pragma unroll
    for (int j = 0; j < 4; ++j) {
      const int gn = n0 + wn + j * 16 + col;
      const float bj = bias[gn];
      #pragma unroll
      for (int i = 0; i < 8; ++i)
        #pragma unroll
        for (int r = 0; r < 4; ++r)
          ((float*)C0)[(m0 + wm + i * 16 + rq + r) * (long)N + gn] =
              acc[i][j][r] + bj;
    }
  } else if (n0 + 256 <= CDIM) {  // whole block in q half (n0 in {0,256,512})
    #pragma unroll
    for (int j = 0; j < 4; ++j) {
      const int gn = n0 + wn + j * 16 + col;
      #pragma unroll
      for (int i = 0; i < 8; ++i)
        #pragma unroll
        for (int r = 0; r < 4; ++r)
          ((__bf16*)C0)[(m0 + wm + i * 16 + rq + r) * (long)CDIM + gn] =
              (__bf16)acc[i][j][r];
    }
  } else {                        // kv half
    #pragma unroll
    for (int j = 0; j < 4; ++j) {
      const int gn = n0 + wn + j * 16 + col - CDIM;
      #pragma unroll
      for (int i = 0; i < 8; ++i)
        #pragma unroll
        for (int r = 0; r < 4; ++r)
          ((__bf16*)C1)[(m0 + wm + i * 16 + rq + r) * (long)EDIM + gn] =
              (__bf16)acc[i][j][r];
    }
  }
}

// ---------------------------------------------------------------------------
// softmax over head_dim (64) on the k half of kv, in place.
// one wave per (token-row, head). grid: TOTTOK*NHEADS/4 blocks of 256.
// ---------------------------------------------------------------------------
__global__ __launch_bounds__(256) void softmax64_kernel(__bf16* __restrict__ kv) {
  long gid = (long)blockIdx.x * 4 + (threadIdx.x >> 6);
  int lane = threadIdx.x & 63;
  long row = gid / NHEADS;
  int h = (int)(gid % NHEADS);
  __bf16* p = kv + row * EDIM + h * HD;
  float v = (float)p[lane];
  float mx = v;
  #pragma unroll
  for (int m = 32; m; m >>= 1) mx = fmaxf(mx, __shfl_xor(mx, m));
  float e = __expf(v - mx);
  float s = e;
  #pragma unroll
  for (int m = 32; m; m >>= 1) s += __shfl_xor(s, m);
  p[lane] = (__bf16)(e / s);
}

// ---------------------------------------------------------------------------
// ktv partials: ktv_part[split][b][h][d][e] = sum_{n in split} ks[b,n,h,d]*v[b,n,h,e]
// grid: (4, NHEADS, NB), block 256 (4 waves, each 16 d-rows x 64 e-cols)
// ---------------------------------------------------------------------------
__global__ __launch_bounds__(256) void ktv_kernel(
    const __bf16* __restrict__ kv, float* __restrict__ ktv_part) {
  const int split = blockIdx.x, h = blockIdx.y, b = blockIdx.z;
  __shared__ __bf16 As[64 * 40];  // [d][n_local]
  __shared__ __bf16 Bs[64 * 40];  // [e][n_local]
  const int tid = threadIdx.x, wave = tid >> 6, lane = tid & 63;
  const int sn = tid >> 3;        // 0..31
  const int sc = (tid & 7) * 8;   // 0..56
  const int fr = lane & 15, fk = (lane >> 4) * 8;
  floatx4 acc[4] = {};
  const long rowbase = (long)b * NTOK * EDIM;

  for (int n0 = split * 1024; n0 < split * 1024 + 1024; n0 += 32) {
    __syncthreads();
    const __bf16* krow = kv + rowbase + (long)(n0 + sn) * EDIM + h * HD + sc;
    const __bf16* vrow = krow + CDIM;
    uint4 ku = *(const uint4*)krow;
    uint4 vu = *(const uint4*)vrow;
    const __bf16* kh = (const __bf16*)&ku;
    const __bf16* vh = (const __bf16*)&vu;
    #pragma unroll
    for (int j = 0; j < 8; ++j) {
      As[(sc + j) * 40 + sn] = kh[j];
      Bs[(sc + j) * 40 + sn] = vh[j];
    }
    __syncthreads();
    bf16x8 af = *(const bf16x8*)&As[(wave * 16 + fr) * 40 + fk];
    #pragma unroll
    for (int j = 0; j < 4; ++j) {
      bf16x8 bf_ = *(const bf16x8*)&Bs[(j * 16 + fr) * 40 + fk];
      acc[j] = __builtin_amdgcn_mfma_f32_16x16x32_bf16(af, bf_, acc[j], 0, 0, 0);
    }
  }

  const int col = lane & 15, rq = (lane >> 4) * 4;
  long base = (((long)split * NB + b) * NHEADS + h) * (HD * HD);
  #pragma unroll
  for (int j = 0; j < 4; ++j)
    #pragma unroll
    for (int r = 0; r < 4; ++r)
      ktv_part[base + (wave * 16 + rq + r) * HD + j * 16 + col] = acc[j][r];
}

// ---------------------------------------------------------------------------
// Build expanded ektv (bf16, [b][H][d][e], H in [0,24)) from the 4 partials,
// applying the head-expansion roll on the flattened (h*64+e) axis.
// ---------------------------------------------------------------------------
__global__ __launch_bounds__(256) void ektv_kernel(
    const float* __restrict__ ktv_part, __bf16* __restrict__ ektv) {
  int idx = blockIdx.x * 256 + threadIdx.x;  // < 8*24*64*64 = 786432
  int e = idx & 63;
  int d = (idx >> 6) & 63;
  int H = (idx >> 12) % 24;
  int b = idx / 98304;
  int c = H * 64 + e;
  int cp = (c < CDIM) ? c : (c - CDIM + 32) % CDIM;
  int hs = cp >> 6, es = cp & 63;
  long o = (((long)b * NHEADS + hs) * HD + d) * HD + es;
  float s = 0.f;
  #pragma unroll
  for (int sp = 0; sp < 4; ++sp)
    s += ktv_part[(long)sp * (NB * NHEADS * HD * HD) + o];
  ektv[idx] = (__bf16)s;
}

// ---------------------------------------------------------------------------
// attn: mid[b, n, H*64+e] = scale * sum_d eq[b,H,n,d] * ektv[b,H,d,e]
// eq columns for head H are q columns (qbase..qbase+63) mod 768.
// grid: (NTOK/128, 24, NB), block 256 (4 waves x 32 token rows).
// ---------------------------------------------------------------------------
__global__ __launch_bounds__(256) void attn_kernel(
    const __bf16* __restrict__ q, const __bf16* __restrict__ ektv,
    __bf16* __restrict__ mid) {
  const int tt = blockIdx.x, H = blockIdx.y, b = blockIdx.z;
  __shared__ __bf16 As[128 * 72];  // [n_local][d]
  __shared__ __bf16 Bs[64 * 72];   // [e][d]
  const int tid = threadIdx.x, wave = tid >> 6, lane = tid & 63;
  const int qbase = (H < NHEADS) ? H * 64 : (H - NHEADS) * 64 + 32;
  const long n0 = (long)b * NTOK + tt * 128;

  {  // stage A (q slice, handling the circular roll per 8-wide chunk)
    int nl = tid >> 1, d0 = (tid & 1) * 32;
    const __bf16* qrow = q + (n0 + nl) * CDIM;
    #pragma unroll
    for (int cch = 0; cch < 4; ++cch) {
      int d = d0 + cch * 8;
      int c0 = qbase + d;
      if (c0 >= CDIM) c0 -= CDIM;
      *(uint4*)&As[nl * 72 + d] = *(const uint4*)(qrow + c0);
    }
  }
  {  // stage B transposed: Bs[e][d] = ektv[b][H][d][e]
    int e = tid & 63, dch = (tid >> 6) * 16;
    const __bf16* src = ektv + ((long)b * 24 + H) * (HD * HD);
    alignas(16) __bf16 tmp[16];
    #pragma unroll
    for (int j = 0; j < 16; ++j) tmp[j] = src[(dch + j) * 64 + e];
    *(uint4*)&Bs[e * 72 + dch] = *(const uint4*)&tmp[0];
    *(uint4*)&Bs[e * 72 + dch + 8] = *(const uint4*)&tmp[8];
  }
  __syncthreads();

  floatx4 acc[2][4] = {};
  const int fr = lane & 15, fk = (lane >> 4) * 8;
  const int wm = wave * 32;
  #pragma unroll
  for (int kk = 0; kk < 64; kk += 32) {
    bf16x8 af0 = *(const bf16x8*)&As[(wm + fr) * 72 + kk + fk];
    bf16x8 af1 = *(const bf16x8*)&As[(wm + 16 + fr) * 72 + kk + fk];
    #pragma unroll
    for (int j = 0; j < 4; ++j) {
      bf16x8 bf_ = *(const bf16x8*)&Bs[(j * 16 + fr) * 72 + kk + fk];
      acc[0][j] = __builtin_amdgcn_mfma_f32_16x16x32_bf16(af0, bf_, acc[0][j], 0, 0, 0);
      acc[1][j] = __builtin_amdgcn_mfma_f32_16x16x32_bf16(af1, bf_, acc[1][j], 0, 0, 0);
    }
  }

  const int col = lane & 15, rq = (lane >> 4) * 4;
  const float scale = 0.125f;  // HEAD_DIM^-0.5
  #pragma unroll
  for (int i = 0; i < 2; ++i)
    #pragma unroll
    for (int j = 0; j < 4; ++j)
      #pragma unroll
      for (int r = 0; r < 4; ++r) {
        long n = n0 + wm + i * 16 + rq + r;
        mid[n * EDIM + H * 64 + j * 16 + col] = (__bf16)(acc[i][j][r] * scale);
      }
}

// ---------------------------------------------------------------------------
// LePE depthwise 3x3 conv, tiled through LDS.
// grid: (12 ch-groups of 64 q-channels, 16 y-groups of 4 rows, NB).
// ---------------------------------------------------------------------------
__global__ __launch_bounds__(256) void lepe_kernel(
    const __bf16* __restrict__ q, const float* __restrict__ w_lepe,
    const float* __restrict__ b_lepe, __bf16* __restrict__ mid) {
  __shared__ __bf16 smem[6 * 64 * 64];  // [row][x][ch], 48 KB
  const int g = blockIdx.x, yg = blockIdx.y, b = blockIdx.z;
  const int y0 = yg * 4;
  const int tid = threadIdx.x;

  #pragma unroll
  for (int k = 0; k < 12; ++k) {
    int v = tid + k * 256;            // 0..3071
    int r = v >> 9;                   // row in slab, 0..5
    int rem = v & 511;
    int x = rem >> 3;
    int chv = (rem & 7) * 8;
    int yy = y0 + r - 1;
    uint4 val = {0u, 0u, 0u, 0u};
    if (yy >= 0 && yy < 64)
      val = *(const uint4*)(q + ((long)(b * NTOK + yy * 64 + x)) * CDIM + g * 64 + chv);
    *(uint4*)&smem[r * 4096 + x * 64 + chv] = val;
  }
  __syncthreads();

  const int ch = tid & 63, xg = tid >> 6;
  const int cq = g * 64 + ch;                 // expanded channel (identity half)
  const int c2 = CDIM + ((cq + 736) % CDIM);  // rolled duplicate channel
  float w1[9], w2[9];
  #pragma unroll
  for (int j = 0; j < 9; ++j) {
    w1[j] = w_lepe[cq * 9 + j];
    w2[j] = w_lepe[c2 * 9 + j];
  }
  const float bias1 = b_lepe[cq], bias2 = b_lepe[c2];

  for (int ly = 0; ly < 4; ++ly) {
    for (int i = 0; i < 16; ++i) {
      int x = xg * 16 + i;
      float a1 = bias1, a2 = bias2;
      #pragma unroll
      for (int r = 0; r < 3; ++r) {
        #pragma unroll
        for (int dx = 0; dx < 3; ++dx) {
          int xx = x + dx - 1;
          if (xx < 0 || xx > 63) continue;  // wave-uniform (xg uniform per wave)
          float v = (float)smem[(ly + r) * 4096 + xx * 64 + ch];
          a1 += w1[r * 3 + dx] * v;
          a2 += w2[r * 3 + dx] * v;
        }
      }
      long o = ((long)(b * NTOK + (y0 + ly) * 64 + x)) * EDIM;
      mid[o + cq] = (__bf16)((float)mid[o + cq] + a1);
      mid[o + c2] = (__bf16)((float)mid[o + c2] + a2);
    }
  }
}

// ---------------------------------------------------------------------------
// launch
// ---------------------------------------------------------------------------
extern "C" void kernel_launch(void* const* d_in, const int* in_sizes, int n_in,
                              void* d_out, int out_size, void* d_ws, size_t ws_size,
                              hipStream_t stream) {
  const float* x      = (const float*)d_in[0];
  const float* w_q    = (const float*)d_in[1];
  const float* w_kv   = (const float*)d_in[2];
  const float* w_proj = (const float*)d_in[3];
  const float* b_proj = (const float*)d_in[4];
  const float* w_lepe = (const float*)d_in[5];
  const float* b_lepe = (const float*)d_in[6];
  float* out = (float*)d_out;

  char* ws = (char*)d_ws;
  __bf16* Wt_qkv = (__bf16*)ws; ws += (long)(CDIM + EDIM) * CDIM * 2;  // 2304x768 (NxK)
  __bf16* Wt_p   = (__bf16*)ws; ws += (long)CDIM * EDIM * 2;           // 768x1536 (NxK)
  __bf16* xb     = (__bf16*)ws; ws += (long)TOTTOK * CDIM * 2;
  __bf16* qb     = (__bf16*)ws; ws += (long)TOTTOK * CDIM * 2;
  __bf16* kvb    = (__bf16*)ws; ws += (long)TOTTOK * EDIM * 2;         // later aliased as mid
  float*  ktv_part = (float*)ws; ws += (long)4 * NB * NHEADS * HD * HD * 4;
  __bf16* ektv   = (__bf16*)ws; ws += (long)NB * 24 * HD * HD * 2;
  __bf16* mid = kvb;  // alias: kv is dead once ektv is built

  // 1. x -> bf16
  f32_to_bf16_kernel<<<(TOTTOK * CDIM) / (256 * 4), 256, 0, stream>>>(
      x, xb, (long)TOTTOK * CDIM);
  // 2. weight transposes (K x N fp32 -> N x K bf16), q|kv concatenated
  transpose_w_kernel<<<dim3(CDIM / 32, CDIM / 32), 256, 0, stream>>>(
      w_q, Wt_qkv, CDIM, CDIM);
  transpose_w_kernel<<<dim3(EDIM / 32, CDIM / 32), 256, 0, stream>>>(
      w_kv, Wt_qkv + (long)CDIM * CDIM, CDIM, EDIM);
  transpose_w_kernel<<<dim3(CDIM / 32, EDIM / 32), 256, 0, stream>>>(
      w_proj, Wt_p, EDIM, CDIM);
  // 3. fused qkv = x @ [w_q | w_kv]  (256^2 8-phase, split epilogue -> qb, kvb)
  //    grid: (32768/256) y-tiles * 9 x-tiles = 1152 blocks
  gemm256_kernel<<<(TOTTOK / 256) * 9, 512, 0, stream>>>(
      xb, Wt_qkv, qb, kvb, nullptr, TOTTOK, CDIM + EDIM, CDIM, 9, 0);
  // 4. softmax over head_dim on k half, in place
  softmax64_kernel<<<(TOTTOK * NHEADS) / 4, 256, 0, stream>>>(kvb);
  // 5. ktv partials (split-K over tokens)
  ktv_kernel<<<dim3(4, NHEADS, NB), 256, 0, stream>>>(kvb, ktv_part);
  // 6. reduce partials + head-expand -> ektv
  ektv_kernel<<<(NB * 24 * HD * HD) / 256, 256, 0, stream>>>(ktv_part, ektv);
  // 7. attn -> mid (overwrites kv buffer)
  attn_kernel<<<dim3(NTOK / 128, 24, NB), 256, 0, stream>>>(qb, ektv, mid);
  // 8. mid += lepe (tiled, LDS-staged)
  lepe_kernel<<<dim3(12, 16, NB), 256, 0, stream>>>(qb, w_lepe, b_lepe, mid);
  // 9. out = mid @ w_proj + b_proj (256^2 8-phase, fp32+bias epilogue)
  //    grid: 128 y-tiles * 3 x-tiles = 384 blocks
  gemm256_kernel<<<(TOTTOK / 256) * 3, 512, 0, stream>>>(
      mid, Wt_p, out, nullptr, b_proj, TOTTOK, CDIM, EDIM, 3, 1);
}

// Round 2
// 656.488 us; speedup vs baseline: 1.0873x; 1.0873x over previous
//
#include <hip/hip_runtime.h>

// ---------------------------------------------------------------------------
// Problem constants: B=8, N=4096 (64x64 image), DIM=768, HEADS=12, HEAD_DIM=64
// EXP=2 -> EDIM=1536, expanded heads = 24.
// ---------------------------------------------------------------------------
#define NB 8
#define NTOK 4096
#define CDIM 768
#define EDIM 1536
#define NHEADS 12
#define HD 64
#define TOTTOK (NB * NTOK)          // 32768

typedef float floatx4 __attribute__((ext_vector_type(4)));
typedef __bf16 bf16x8 __attribute__((ext_vector_type(8)));

// async 16B global -> LDS (lane-contiguous LDS dest: wave base + lane*16)
__device__ __forceinline__ void gld16(const __bf16* g, void* l) {
  __builtin_amdgcn_global_load_lds(
      (const __attribute__((address_space(1))) unsigned int*)g,
      (__attribute__((address_space(3))) unsigned int*)l, 16, 0, 0);
}

#define MFMA16(a, b, c) __builtin_amdgcn_mfma_f32_16x16x32_bf16(a, b, c, 0, 0, 0)
#define FENCE() asm volatile("" ::: "memory")
#define BARRIER() do { FENCE(); __builtin_amdgcn_s_barrier(); FENCE(); } while (0)

// ---------------------------------------------------------------------------
// fp32 -> bf16 elementwise convert (x)
// ---------------------------------------------------------------------------
__global__ __launch_bounds__(256) void f32_to_bf16_kernel(
    const float* __restrict__ in, __bf16* __restrict__ out, long n) {
  long i = ((long)blockIdx.x * 256 + threadIdx.x) * 4;
  if (i >= n) return;
  float4 f = *(const float4*)(in + i);
  alignas(8) __bf16 h[4];
  h[0] = (__bf16)f.x; h[1] = (__bf16)f.y; h[2] = (__bf16)f.z; h[3] = (__bf16)f.w;
  *(unsigned long long*)(out + i) = *(const unsigned long long*)h;
}

// ---------------------------------------------------------------------------
// W (K x N fp32, row-major) -> Wt (N x K bf16, row-major)
// grid: (N/32, K/32), block 256
// ---------------------------------------------------------------------------
__global__ __launch_bounds__(256) void transpose_w_kernel(
    const float* __restrict__ W, __bf16* __restrict__ Wt, int K, int N) {
  __shared__ float tile[32][33];
  int nb = blockIdx.x * 32, kb = blockIdx.y * 32;
  int tx = threadIdx.x & 31, ty = threadIdx.x >> 5;  // ty 0..7
  #pragma unroll
  for (int i = ty; i < 32; i += 8)
    tile[i][tx] = W[(long)(kb + i) * N + nb + tx];
  __syncthreads();
  #pragma unroll
  for (int i = ty; i < 32; i += 8)
    Wt[(long)(nb + i) * K + kb + tx] = (__bf16)tile[tx][i];
}

// ---------------------------------------------------------------------------
// 256x256 8-phase bf16 MFMA GEMM (T2+T3+T4+T5). Used for the qkv GEMM.
// C(MxN) = A(MxK) @ Bt(NxK)^T. BK=64, 512 threads = 8 waves (2M x 4N),
// per-wave output 128x64 (acc[8][4] 16x16 frags), LDS 128 KiB (2-deep dbuf).
//
// Staging: per K-tile, 8 slices of 64 rows x 64 cols (A0..A3, B0..B3); each
// slice = 1 global_load_lds_dwordx4 per wave. LDS dest linear; chunk XOR
// swizzle (stored chunk s at row r holds logical s^(r&7)) applied by
// pre-swizzling the per-lane GLOBAL source (both-sides swizzle, rule #21).
//
// Schedule (tile t computes buf[t&1], stages t+1 -> buf[~t&1]):
//   ph1: read af-lo(8) + bf01(4) | issue ALL 8 loads (B0..B3,A0,A2,A1,A3)
//   ph2: read bf23(4)            | vmcnt(8)  [retires A1,A3(t), 5-ph slack]
//   ph3: read af-hi(8)           | (bf23 kept in regs)
//   ph4: no reads                | vmcnt(2)  [retires B0-3,A0,A2(t+1), 3-ph]
// Invariant entering each tile: only A1,A3(t) in flight. ph1 needs A0,A2 +
// all B (covered by prev ph4's vmcnt(2)); ph3 needs A1,A3 (covered by ph2).
// bf01 kept in regs through ph4 (no re-read). vmcnt never 0 in main loop;
// last tile: ph2 drains vmcnt(0).
//
// Block swizzle: flat&7 = XCD owns a contiguous y-strip; needs (M/256)%8==0.
// mode 0: split bf16 epilogue (cols<768 -> C0 stride 768; else C1 stride 1536)
// mode 1: fp32 + bias epilogue into C0 stride N.
// ---------------------------------------------------------------------------
__global__ __launch_bounds__(512, 2) void gemm256_kernel(
    const __bf16* __restrict__ A, const __bf16* __restrict__ Bt,
    void* __restrict__ C0, void* __restrict__ C1,
    const float* __restrict__ bias,
    int M, int N, int K, int nxb, int mode) {
  __shared__ __bf16 As[2][256 * 64];   // 64 KB
  __shared__ __bf16 Bs[2][256 * 64];   // 64 KB
  const int tid = threadIdx.x;
  const int wave = tid >> 6, lane = tid & 63;

  const int flat = blockIdx.x;
  const int xcd = flat & 7, rem = flat >> 3;
  const int per = (M >> 8) >> 3;           // y-tiles per XCD
  const int yb = xcd * per + rem / nxb;
  const int xb = rem % nxb;
  const long m0 = (long)yb * 256;
  const int n0 = xb * 256;

  const int wm = (wave >> 2) * 128;        // M-half of this wave
  const int wn = (wave & 3) * 64;          // N-quarter of this wave

  // staging: wave covers rows [wave*8, wave*8+8) of each 64-row slice.
  const int srow = lane >> 3;              // 0..7 == row&7
  const int gchunk = (lane & 7) ^ srow;
  const __bf16* Ag = A + (m0 + wave * 8 + srow) * (long)K + gchunk * 8;
  const __bf16* Bg = Bt + ((long)n0 + wave * 8 + srow) * (long)K + gchunk * 8;
  const long slabK = 64 * (long)K;         // global elems between slices

  const int fr = lane & 15, qh = lane >> 4;
  const int c0 = ((qh ^ (fr & 7)) << 3);        // stored-chunk offset, kk=0
  const int c1 = (((qh + 4) ^ (fr & 7)) << 3);  // stored-chunk offset, kk=1

  floatx4 acc[8][4] = {};
  bf16x8 afl[4][2], bf01[2][2], bf23[2][2];
  const int nt = K >> 6;

  // prologue: stage tile 0; order B0..B3, A0, A2, A1, A3 (A1,A3 newest)
  {
    char* al = (char*)&As[0][0] + wave * 1024;
    char* bl = (char*)&Bs[0][0] + wave * 1024;
    gld16(Bg + 0 * slabK, bl + 0 * 8192);
    gld16(Bg + 1 * slabK, bl + 1 * 8192);
    gld16(Bg + 2 * slabK, bl + 2 * 8192);
    gld16(Bg + 3 * slabK, bl + 3 * 8192);
    gld16(Ag + 0 * slabK, al + 0 * 8192);
    gld16(Ag + 2 * slabK, al + 2 * 8192);
    gld16(Ag + 1 * slabK, al + 1 * 8192);
    gld16(Ag + 3 * slabK, al + 3 * 8192);
  }
  asm volatile("s_waitcnt vmcnt(2)" ::: "memory");  // A1,A3 stay in flight
  BARRIER();

  for (int t = 0; t < nt; ++t) {
    const int cur = t & 1;
    const bool pf = (t + 1 < nt);
    const __bf16* Ac = &As[cur][0];
    const __bf16* Bc = &Bs[cur][0];
    const __bf16* an = Ag + (t + 1) * 64;
    const __bf16* bn = Bg + (t + 1) * 64;
    char* al = (char*)&As[cur ^ 1][0] + wave * 1024;
    char* bl = (char*)&Bs[cur ^ 1][0] + wave * 1024;

    // ---- phase 1: (m-lo x n01); issue all 8 prefetch loads ---------------
    #pragma unroll
    for (int i = 0; i < 4; ++i) {
      const __bf16* p = &Ac[(wm + i * 16 + fr) * 64];
      afl[i][0] = *(const bf16x8*)(p + c0);
      afl[i][1] = *(const bf16x8*)(p + c1);
    }
    #pragma unroll
    for (int j = 0; j < 2; ++j) {
      const __bf16* p = &Bc[(wn + j * 16 + fr) * 64];
      bf01[j][0] = *(const bf16x8*)(p + c0);
      bf01[j][1] = *(const bf16x8*)(p + c1);
    }
    if (pf) {
      gld16(bn + 0 * slabK, bl + 0 * 8192);
      gld16(bn + 1 * slabK, bl + 1 * 8192);
      gld16(bn + 2 * slabK, bl + 2 * 8192);
      gld16(bn + 3 * slabK, bl + 3 * 8192);
      gld16(an + 0 * slabK, al + 0 * 8192);
      gld16(an + 2 * slabK, al + 2 * 8192);
      gld16(an + 1 * slabK, al + 1 * 8192);
      gld16(an + 3 * slabK, al + 3 * 8192);
    }
    BARRIER();
    asm volatile("s_waitcnt lgkmcnt(0)");
    __builtin_amdgcn_sched_barrier(0);
    __builtin_amdgcn_s_setprio(1);
    #pragma unroll
    for (int i = 0; i < 4; ++i)
      #pragma unroll
      for (int j = 0; j < 2; ++j) {
        acc[i][j] = MFMA16(afl[i][0], bf01[j][0], acc[i][j]);
        acc[i][j] = MFMA16(afl[i][1], bf01[j][1], acc[i][j]);
      }
    __builtin_amdgcn_s_setprio(0);
    BARRIER();

    // ---- phase 2: (m-lo x n23) -------------------------------------------
    #pragma unroll
    for (int j = 0; j < 2; ++j) {
      const __bf16* p = &Bc[(wn + (2 + j) * 16 + fr) * 64];
      bf23[j][0] = *(const bf16x8*)(p + c0);
      bf23[j][1] = *(const bf16x8*)(p + c1);
    }
    if (pf) {
      asm volatile("s_waitcnt vmcnt(8)" ::: "memory");  // retire A1,A3(t)
    } else {
      asm volatile("s_waitcnt vmcnt(0)" ::: "memory");  // last tile: drain
    }
    BARRIER();
    asm volatile("s_waitcnt lgkmcnt(0)");
    __builtin_amdgcn_sched_barrier(0);
    __builtin_amdgcn_s_setprio(1);
    #pragma unroll
    for (int i = 0; i < 4; ++i)
      #pragma unroll
      for (int j = 0; j < 2; ++j) {
        acc[i][2 + j] = MFMA16(afl[i][0], bf23[j][0], acc[i][2 + j]);
        acc[i][2 + j] = MFMA16(afl[i][1], bf23[j][1], acc[i][2 + j]);
      }
    __builtin_amdgcn_s_setprio(0);
    BARRIER();

    // ---- phase 3: (m-hi x n23), bf23 still in regs -----------------------
    #pragma unroll
    for (int i = 0; i < 4; ++i) {
      const __bf16* p = &Ac[(wm + (4 + i) * 16 + fr) * 64];
      afl[i][0] = *(const bf16x8*)(p + c0);
      afl[i][1] = *(const bf16x8*)(p + c1);
    }
    BARRIER();
    asm volatile("s_waitcnt lgkmcnt(0)");
    __builtin_amdgcn_sched_barrier(0);
    __builtin_amdgcn_s_setprio(1);
    #pragma unroll
    for (int i = 0; i < 4; ++i)
      #pragma unroll
      for (int j = 0; j < 2; ++j) {
        acc[4 + i][2 + j] = MFMA16(afl[i][0], bf23[j][0], acc[4 + i][2 + j]);
        acc[4 + i][2 + j] = MFMA16(afl[i][1], bf23[j][1], acc[4 + i][2 + j]);
      }
    __builtin_amdgcn_s_setprio(0);
    BARRIER();

    // ---- phase 4: (m-hi x n01), bf01 still in regs -----------------------
    if (pf) {
      asm volatile("s_waitcnt vmcnt(2)" ::: "memory");  // B0-3,A0,A2(t+1) in
    }
    __builtin_amdgcn_sched_barrier(0);
    BARRIER();
    __builtin_amdgcn_s_setprio(1);
    #pragma unroll
    for (int i = 0; i < 4; ++i)
      #pragma unroll
      for (int j = 0; j < 2; ++j) {
        acc[4 + i][j] = MFMA16(afl[i][0], bf01[j][0], acc[4 + i][j]);
        acc[4 + i][j] = MFMA16(afl[i][1], bf01[j][1], acc[4 + i][j]);
      }
    __builtin_amdgcn_s_setprio(0);
    BARRIER();
  }

  // epilogue
  const int col = lane & 15, rq = (lane >> 4) * 4;
  if (mode == 1) {
    #pragma unroll
    for (int j = 0; j < 4; ++j) {
      const int gn = n0 + wn + j * 16 + col;
      const float bj = bias[gn];
      #pragma unroll
      for (int i = 0; i < 8; ++i)
        #pragma unroll
        for (int r = 0; r < 4; ++r)
          ((float*)C0)[(m0 + wm + i * 16 + rq + r) * (long)N + gn] =
              acc[i][j][r] + bj;
    }
  } else if (n0 + 256 <= CDIM) {  // whole block in q half (n0 in {0,256,512})
    #pragma unroll
    for (int j = 0; j < 4; ++j) {
      const int gn = n0 + wn + j * 16 + col;
      #pragma unroll
      for (int i = 0; i < 8; ++i)
        #pragma unroll
        for (int r = 0; r < 4; ++r)
          ((__bf16*)C0)[(m0 + wm + i * 16 + rq + r) * (long)CDIM + gn] =
              (__bf16)acc[i][j][r];
    }
  } else {                        // kv half
    #pragma unroll
    for (int j = 0; j < 4; ++j) {
      const int gn = n0 + wn + j * 16 + col - CDIM;
      #pragma unroll
      for (int i = 0; i < 8; ++i)
        #pragma unroll
        for (int r = 0; r < 4; ++r)
          ((__bf16*)C1)[(m0 + wm + i * 16 + rq + r) * (long)EDIM + gn] =
              (__bf16)acc[i][j][r];
    }
  }
}

// ---------------------------------------------------------------------------
// 128x128 bf16 MFMA GEMM (m97 structure). Used for the proj GEMM (better
// grid packing: 256-thread blocks, 32 KB LDS -> ~2-3 blocks/CU).
// mode 1: fp32 + bias epilogue into C0 stride N.
// ---------------------------------------------------------------------------
__global__ __launch_bounds__(256) void gemm_glds_kernel(
    const __bf16* __restrict__ A, const __bf16* __restrict__ Bt,
    void* __restrict__ C0, void* __restrict__ C1,
    const float* __restrict__ bias,
    int M, int N, int K, int nxb, int mode) {
  __shared__ __bf16 As[128 * 32];
  __shared__ __bf16 Bs[128 * 32];
  const int tid = threadIdx.x;
  const int wave = tid >> 6, lane = tid & 63;

  const int flat = blockIdx.x;
  const int xcd = flat & 7, rem = flat >> 3;
  const int per = (M >> 7) >> 3;           // y-tiles per XCD
  const int yb = xcd * per + rem / nxb;
  const int xb = rem % nxb;
  const long m0 = (long)yb * 128;
  const int n0 = xb * 128;

  const int wm = (wave >> 1) * 64, wn = (wave & 1) * 64;

  const int srow = lane >> 2;
  const int gchunk = (lane & 3) ^ ((lane >> 3) & 3);
  const __bf16* Ag = A + (m0 + wave * 16 + srow) * (long)K + gchunk * 8;
  const __bf16* Bg = Bt + ((long)n0 + wave * 16 + srow) * (long)K + gchunk * 8;
  char* Al = (char*)As + wave * 16 * 64;   // + lane*16 applied by HW
  char* Bl = (char*)Bs + wave * 16 * 64;
  const long rowskip = 64 * (long)K;

  const int fr = lane & 15;
  const int csw = ((lane >> 4) ^ ((fr >> 1) & 3)) * 8;  // swizzled k-chunk

  floatx4 acc[4][4] = {};

  for (int k0 = 0; k0 < K; k0 += 32) {
    __syncthreads();
    gld16(Ag + k0, Al);
    gld16(Ag + k0 + rowskip, Al + 64 * 64);
    gld16(Bg + k0, Bl);
    gld16(Bg + k0 + rowskip, Bl + 64 * 64);
    __syncthreads();   // compiler drains vmcnt before s_barrier
    bf16x8 af[4], bfr[4];
    #pragma unroll
    for (int i = 0; i < 4; ++i)
      af[i] = *(const bf16x8*)&As[(wm + i * 16 + fr) * 32 + csw];
    #pragma unroll
    for (int j = 0; j < 4; ++j)
      bfr[j] = *(const bf16x8*)&Bs[(wn + j * 16 + fr) * 32 + csw];
    #pragma unroll
    for (int i = 0; i < 4; ++i)
      #pragma unroll
      for (int j = 0; j < 4; ++j)
        acc[i][j] = __builtin_amdgcn_mfma_f32_16x16x32_bf16(af[i], bfr[j], acc[i][j], 0, 0, 0);
  }

  const int col = lane & 15, rq = (lane >> 4) * 4;
  if (mode == 1) {
    #pragma unroll
    for (int i = 0; i < 4; ++i)
      #pragma unroll
      for (int j = 0; j < 4; ++j)
        #pragma unroll
        for (int r = 0; r < 4; ++r) {
          long gm = m0 + wm + i * 16 + rq + r;
          int gn = n0 + wn + j * 16 + col;
          ((float*)C0)[gm * N + gn] = acc[i][j][r] + bias[gn];
        }
  } else {
    if (n0 + 128 <= CDIM) {
      #pragma unroll
      for (int i = 0; i < 4; ++i)
        #pragma unroll
        for (int j = 0; j < 4; ++j)
          #pragma unroll
          for (int r = 0; r < 4; ++r) {
            long gm = m0 + wm + i * 16 + rq + r;
            int gn = n0 + wn + j * 16 + col;
            ((__bf16*)C0)[gm * CDIM + gn] = (__bf16)acc[i][j][r];
          }
    } else {
      #pragma unroll
      for (int i = 0; i < 4; ++i)
        #pragma unroll
        for (int j = 0; j < 4; ++j)
          #pragma unroll
          for (int r = 0; r < 4; ++r) {
            long gm = m0 + wm + i * 16 + rq + r;
            int gn = n0 + wn + j * 16 + col - CDIM;
            ((__bf16*)C1)[gm * EDIM + gn] = (__bf16)acc[i][j][r];
          }
    }
  }
}

// ---------------------------------------------------------------------------
// ktv partials with FUSED softmax over head_dim:
// ktv_part[split][b][h][d][e] = sum_{n in split} softmax(k[b,n,h,:])[d]*v[b,n,h,e]
// grid: (4, NHEADS, NB), block 256 (4 waves, each 16 d-rows x 64 e-cols).
// Softmax: the 8 lanes sharing a k-row (sn) hold its 64 values (8 each);
// 3-step shfl_xor max/sum within the 8-lane group, then normalize.
// ---------------------------------------------------------------------------
__global__ __launch_bounds__(256) void ktv_kernel(
    const __bf16* __restrict__ kv, float* __restrict__ ktv_part) {
  const int split = blockIdx.x, h = blockIdx.y, b = blockIdx.z;
  __shared__ __bf16 As[64 * 40];  // [d][n_local]
  __shared__ __bf16 Bs[64 * 40];  // [e][n_local]
  const int tid = threadIdx.x, wave = tid >> 6, lane = tid & 63;
  const int sn = tid >> 3;        // 0..31
  const int sc = (tid & 7) * 8;   // 0..56
  const int fr = lane & 15, fk = (lane >> 4) * 8;
  floatx4 acc[4] = {};
  const long rowbase = (long)b * NTOK * EDIM;

  for (int n0 = split * 1024; n0 < split * 1024 + 1024; n0 += 32) {
    __syncthreads();
    const __bf16* krow = kv + rowbase + (long)(n0 + sn) * EDIM + h * HD + sc;
    const __bf16* vrow = krow + CDIM;
    uint4 ku = *(const uint4*)krow;
    uint4 vu = *(const uint4*)vrow;
    const __bf16* kh = (const __bf16*)&ku;
    const __bf16* vh = (const __bf16*)&vu;
    // fused softmax over this row's 64 k values (8 lanes x 8 elems)
    float kf[8];
    float mx = -1e30f;
    #pragma unroll
    for (int j = 0; j < 8; ++j) { kf[j] = (float)kh[j]; mx = fmaxf(mx, kf[j]); }
    #pragma unroll
    for (int m = 1; m < 8; m <<= 1) mx = fmaxf(mx, __shfl_xor(mx, m));
    float s = 0.f;
    #pragma unroll
    for (int j = 0; j < 8; ++j) { kf[j] = __expf(kf[j] - mx); s += kf[j]; }
    #pragma unroll
    for (int m = 1; m < 8; m <<= 1) s += __shfl_xor(s, m);
    const float inv = 1.f / s;
    #pragma unroll
    for (int j = 0; j < 8; ++j) {
      As[(sc + j) * 40 + sn] = (__bf16)(kf[j] * inv);
      Bs[(sc + j) * 40 + sn] = vh[j];
    }
    __syncthreads();
    bf16x8 af = *(const bf16x8*)&As[(wave * 16 + fr) * 40 + fk];
    #pragma unroll
    for (int j = 0; j < 4; ++j) {
      bf16x8 bf_ = *(const bf16x8*)&Bs[(j * 16 + fr) * 40 + fk];
      acc[j] = __builtin_amdgcn_mfma_f32_16x16x32_bf16(af, bf_, acc[j], 0, 0, 0);
    }
  }

  const int col = lane & 15, rq = (lane >> 4) * 4;
  long base = (((long)split * NB + b) * NHEADS + h) * (HD * HD);
  #pragma unroll
  for (int j = 0; j < 4; ++j)
    #pragma unroll
    for (int r = 0; r < 4; ++r)
      ktv_part[base + (wave * 16 + rq + r) * HD + j * 16 + col] = acc[j][r];
}

// ---------------------------------------------------------------------------
// Build expanded ektv (bf16, [b][H][d][e], H in [0,24)) from the 4 partials,
// applying the head-expansion roll on the flattened (h*64+e) axis.
// ---------------------------------------------------------------------------
__global__ __launch_bounds__(256) void ektv_kernel(
    const float* __restrict__ ktv_part, __bf16* __restrict__ ektv) {
  int idx = blockIdx.x * 256 + threadIdx.x;  // < 8*24*64*64 = 786432
  int e = idx & 63;
  int d = (idx >> 6) & 63;
  int H = (idx >> 12) % 24;
  int b = idx / 98304;
  int c = H * 64 + e;
  int cp = (c < CDIM) ? c : (c - CDIM + 32) % CDIM;
  int hs = cp >> 6, es = cp & 63;
  long o = (((long)b * NHEADS + hs) * HD + d) * HD + es;
  float s = 0.f;
  #pragma unroll
  for (int sp = 0; sp < 4; ++sp)
    s += ktv_part[(long)sp * (NB * NHEADS * HD * HD) + o];
  ektv[idx] = (__bf16)s;
}

// ---------------------------------------------------------------------------
// attn: mid[b, n, H*64+e] = scale * sum_d eq[b,H,n,d] * ektv[b,H,d,e]
// eq columns for head H are q columns (qbase..qbase+63) mod 768.
// grid: (NTOK/128, 24, NB), block 256 (4 waves x 32 token rows).
// ---------------------------------------------------------------------------
__global__ __launch_bounds__(256) void attn_kernel(
    const __bf16* __restrict__ q, const __bf16* __restrict__ ektv,
    __bf16* __restrict__ mid) {
  const int tt = blockIdx.x, H = blockIdx.y, b = blockIdx.z;
  __shared__ __bf16 As[128 * 72];  // [n_local][d]
  __shared__ __bf16 Bs[64 * 72];   // [e][d]
  const int tid = threadIdx.x, wave = tid >> 6, lane = tid & 63;
  const int qbase = (H < NHEADS) ? H * 64 : (H - NHEADS) * 64 + 32;
  const long n0 = (long)b * NTOK + tt * 128;

  {  // stage A (q slice, handling the circular roll per 8-wide chunk)
    int nl = tid >> 1, d0 = (tid & 1) * 32;
    const __bf16* qrow = q + (n0 + nl) * CDIM;
    #pragma unroll
    for (int cch = 0; cch < 4; ++cch) {
      int d = d0 + cch * 8;
      int c0 = qbase + d;
      if (c0 >= CDIM) c0 -= CDIM;
      *(uint4*)&As[nl * 72 + d] = *(const uint4*)(qrow + c0);
    }
  }
  {  // stage B transposed: Bs[e][d] = ektv[b][H][d][e]
    int e = tid & 63, dch = (tid >> 6) * 16;
    const __bf16* src = ektv + ((long)b * 24 + H) * (HD * HD);
    alignas(16) __bf16 tmp[16];
    #pragma unroll
    for (int j = 0; j < 16; ++j) tmp[j] = src[(dch + j) * 64 + e];
    *(uint4*)&Bs[e * 72 + dch] = *(const uint4*)&tmp[0];
    *(uint4*)&Bs[e * 72 + dch + 8] = *(const uint4*)&tmp[8];
  }
  __syncthreads();

  floatx4 acc[2][4] = {};
  const int fr = lane & 15, fk = (lane >> 4) * 8;
  const int wm = wave * 32;
  #pragma unroll
  for (int kk = 0; kk < 64; kk += 32) {
    bf16x8 af0 = *(const bf16x8*)&As[(wm + fr) * 72 + kk + fk];
    bf16x8 af1 = *(const bf16x8*)&As[(wm + 16 + fr) * 72 + kk + fk];
    #pragma unroll
    for (int j = 0; j < 4; ++j) {
      bf16x8 bf_ = *(const bf16x8*)&Bs[(j * 16 + fr) * 72 + kk + fk];
      acc[0][j] = __builtin_amdgcn_mfma_f32_16x16x32_bf16(af0, bf_, acc[0][j], 0, 0, 0);
      acc[1][j] = __builtin_amdgcn_mfma_f32_16x16x32_bf16(af1, bf_, acc[1][j], 0, 0, 0);
    }
  }

  const int col = lane & 15, rq = (lane >> 4) * 4;
  const float scale = 0.125f;  // HEAD_DIM^-0.5
  #pragma unroll
  for (int i = 0; i < 2; ++i)
    #pragma unroll
    for (int j = 0; j < 4; ++j)
      #pragma unroll
      for (int r = 0; r < 4; ++r) {
        long n = n0 + wm + i * 16 + rq + r;
        mid[n * EDIM + H * 64 + j * 16 + col] = (__bf16)(acc[i][j][r] * scale);
      }
}

// ---------------------------------------------------------------------------
// LePE depthwise 3x3 conv, tiled through LDS, sliding-window register reuse:
// per x-step load only the new column (6 rows) and reuse the 3-col window
// across the 4 output rows and both expanded channels (6 reads / 8 outputs
// instead of 9 reads per output).
// grid: (12 ch-groups of 64 q-channels, 16 y-groups of 4 rows, NB).
// ---------------------------------------------------------------------------
__global__ __launch_bounds__(256) void lepe_kernel(
    const __bf16* __restrict__ q, const float* __restrict__ w_lepe,
    const float* __restrict__ b_lepe, __bf16* __restrict__ mid) {
  __shared__ __bf16 smem[6 * 64 * 64];  // [row][x][ch], 48 KB
  const int g = blockIdx.x, yg = blockIdx.y, b = blockIdx.z;
  const int y0 = yg * 4;
  const int tid = threadIdx.x;

  #pragma unroll
  for (int k = 0; k < 12; ++k) {
    int v = tid + k * 256;            // 0..3071
    int r = v >> 9;                   // row in slab, 0..5
    int rem = v & 511;
    int x = rem >> 3;
    int chv = (rem & 7) * 8;
    int yy = y0 + r - 1;
    uint4 val = {0u, 0u, 0u, 0u};
    if (yy >= 0 && yy < 64)
      val = *(const uint4*)(q + ((long)(b * NTOK + yy * 64 + x)) * CDIM + g * 64 + chv);
    *(uint4*)&smem[r * 4096 + x * 64 + chv] = val;
  }
  __syncthreads();

  const int ch = tid & 63, xg = tid >> 6;
  const int cq = g * 64 + ch;                 // expanded channel (identity half)
  const int c2 = CDIM + ((cq + 736) % CDIM);  // rolled duplicate channel
  float w1[9], w2[9];
  #pragma unroll
  for (int j = 0; j < 9; ++j) {
    w1[j] = w_lepe[cq * 9 + j];
    w2[j] = w_lepe[c2 * 9 + j];
  }
  const float bias1 = b_lepe[cq], bias2 = b_lepe[c2];

  const int x0 = xg * 16;
  float cm[6], cc[6], cp[6];
  #pragma unroll
  for (int r = 0; r < 6; ++r) {
    cm[r] = (x0 > 0) ? (float)smem[r * 4096 + (x0 - 1) * 64 + ch] : 0.f;  // wave-uniform cond
    cc[r] = (float)smem[r * 4096 + x0 * 64 + ch];
  }
  #pragma unroll
  for (int i = 0; i < 16; ++i) {
    const int x = x0 + i;
    #pragma unroll
    for (int r = 0; r < 6; ++r)
      cp[r] = (x < 63) ? (float)smem[r * 4096 + (x + 1) * 64 + ch] : 0.f;  // wave-uniform
    #pragma unroll
    for (int ly = 0; ly < 4; ++ly) {
      float a1 = bias1, a2 = bias2;
      #pragma unroll
      for (int r = 0; r < 3; ++r) {
        const float vm = cm[ly + r], vc = cc[ly + r], vp = cp[ly + r];
        a1 += w1[r * 3 + 0] * vm + w1[r * 3 + 1] * vc + w1[r * 3 + 2] * vp;
        a2 += w2[r * 3 + 0] * vm + w2[r * 3 + 1] * vc + w2[r * 3 + 2] * vp;
      }
      long o = ((long)(b * NTOK + (y0 + ly) * 64 + x)) * EDIM;
      mid[o + cq] = (__bf16)((float)mid[o + cq] + a1);
      mid[o + c2] = (__bf16)((float)mid[o + c2] + a2);
    }
    #pragma unroll
    for (int r = 0; r < 6; ++r) { cm[r] = cc[r]; cc[r] = cp[r]; }
  }
}

// ---------------------------------------------------------------------------
// launch
// ---------------------------------------------------------------------------
extern "C" void kernel_launch(void* const* d_in, const int* in_sizes, int n_in,
                              void* d_out, int out_size, void* d_ws, size_t ws_size,
                              hipStream_t stream) {
  const float* x      = (const float*)d_in[0];
  const float* w_q    = (const float*)d_in[1];
  const float* w_kv   = (const float*)d_in[2];
  const float* w_proj = (const float*)d_in[3];
  const float* b_proj = (const float*)d_in[4];
  const float* w_lepe = (const float*)d_in[5];
  const float* b_lepe = (const float*)d_in[6];
  float* out = (float*)d_out;

  char* ws = (char*)d_ws;
  __bf16* Wt_qkv = (__bf16*)ws; ws += (long)(CDIM + EDIM) * CDIM * 2;  // 2304x768 (NxK)
  __bf16* Wt_p   = (__bf16*)ws; ws += (long)CDIM * EDIM * 2;           // 768x1536 (NxK)
  __bf16* xb     = (__bf16*)ws; ws += (long)TOTTOK * CDIM * 2;
  __bf16* qb     = (__bf16*)ws; ws += (long)TOTTOK * CDIM * 2;
  __bf16* kvb    = (__bf16*)ws; ws += (long)TOTTOK * EDIM * 2;         // later aliased as mid
  float*  ktv_part = (float*)ws; ws += (long)4 * NB * NHEADS * HD * HD * 4;
  __bf16* ektv   = (__bf16*)ws; ws += (long)NB * 24 * HD * HD * 2;
  __bf16* mid = kvb;  // alias: kv is dead once ektv is built

  // 1. x -> bf16
  f32_to_bf16_kernel<<<(TOTTOK * CDIM) / (256 * 4), 256, 0, stream>>>(
      x, xb, (long)TOTTOK * CDIM);
  // 2. weight transposes (K x N fp32 -> N x K bf16), q|kv concatenated
  transpose_w_kernel<<<dim3(CDIM / 32, CDIM / 32), 256, 0, stream>>>(
      w_q, Wt_qkv, CDIM, CDIM);
  transpose_w_kernel<<<dim3(EDIM / 32, CDIM / 32), 256, 0, stream>>>(
      w_kv, Wt_qkv + (long)CDIM * CDIM, CDIM, EDIM);
  transpose_w_kernel<<<dim3(CDIM / 32, EDIM / 32), 256, 0, stream>>>(
      w_proj, Wt_p, EDIM, CDIM);
  // 3. fused qkv = x @ [w_q | w_kv]  (256^2 8-phase, split epilogue -> qb, kvb)
  //    grid: (32768/256) y-tiles * 9 x-tiles = 1152 blocks
  gemm256_kernel<<<(TOTTOK / 256) * 9, 512, 0, stream>>>(
      xb, Wt_qkv, qb, kvb, nullptr, TOTTOK, CDIM + EDIM, CDIM, 9, 0);
  // 4. ktv partials (softmax fused into staging; split-K over tokens)
  ktv_kernel<<<dim3(4, NHEADS, NB), 256, 0, stream>>>(kvb, ktv_part);
  // 5. reduce partials + head-expand -> ektv
  ektv_kernel<<<(NB * 24 * HD * HD) / 256, 256, 0, stream>>>(ktv_part, ektv);
  // 6. attn -> mid (overwrites kv buffer)
  attn_kernel<<<dim3(NTOK / 128, 24, NB), 256, 0, stream>>>(qb, ektv, mid);
  // 7. mid += lepe (tiled, LDS-staged, sliding-window)
  lepe_kernel<<<dim3(12, 16, NB), 256, 0, stream>>>(qb, w_lepe, b_lepe, mid);
  // 8. out = mid @ w_proj + b_proj (128^2 m97 structure: better packing)
  //    grid: 256 y-tiles * 6 x-tiles = 1536 blocks
  gemm_glds_kernel<<<(TOTTOK / 128) * 6, 256, 0, stream>>>(
      mid, Wt_p, out, nullptr, b_proj, TOTTOK, CDIM, EDIM, 6, 1);
}

// Round 3
// 628.042 us; speedup vs baseline: 1.1365x; 1.0453x over previous
//
#include <hip/hip_runtime.h>

// ---------------------------------------------------------------------------
// Problem constants: B=8, N=4096 (64x64 image), DIM=768, HEADS=12, HEAD_DIM=64
// EXP=2 -> EDIM=1536, expanded heads = 24.
// ---------------------------------------------------------------------------
#define NB 8
#define NTOK 4096
#define CDIM 768
#define EDIM 1536
#define NHEADS 12
#define HD 64
#define TOTTOK (NB * NTOK)          // 32768

typedef float floatx4 __attribute__((ext_vector_type(4)));
typedef __bf16 bf16x8 __attribute__((ext_vector_type(8)));

// async 16B global -> LDS (lane-contiguous LDS dest: wave base + lane*16)
__device__ __forceinline__ void gld16(const __bf16* g, void* l) {
  __builtin_amdgcn_global_load_lds(
      (const __attribute__((address_space(1))) unsigned int*)g,
      (__attribute__((address_space(3))) unsigned int*)l, 16, 0, 0);
}

#define MFMA16(a, b, c) __builtin_amdgcn_mfma_f32_16x16x32_bf16(a, b, c, 0, 0, 0)
#define FENCE() asm volatile("" ::: "memory")
#define BARRIER() do { FENCE(); __builtin_amdgcn_s_barrier(); FENCE(); } while (0)

// ---------------------------------------------------------------------------
// fp32 -> bf16 elementwise convert (x)
// ---------------------------------------------------------------------------
__global__ __launch_bounds__(256) void f32_to_bf16_kernel(
    const float* __restrict__ in, __bf16* __restrict__ out, long n) {
  long i = ((long)blockIdx.x * 256 + threadIdx.x) * 4;
  if (i >= n) return;
  float4 f = *(const float4*)(in + i);
  alignas(8) __bf16 h[4];
  h[0] = (__bf16)f.x; h[1] = (__bf16)f.y; h[2] = (__bf16)f.z; h[3] = (__bf16)f.w;
  *(unsigned long long*)(out + i) = *(const unsigned long long*)h;
}

// ---------------------------------------------------------------------------
// W (K x N fp32, row-major) -> Wt (N x K bf16, row-major)
// grid: (N/32, K/32), block 256
// ---------------------------------------------------------------------------
__global__ __launch_bounds__(256) void transpose_w_kernel(
    const float* __restrict__ W, __bf16* __restrict__ Wt, int K, int N) {
  __shared__ float tile[32][33];
  int nb = blockIdx.x * 32, kb = blockIdx.y * 32;
  int tx = threadIdx.x & 31, ty = threadIdx.x >> 5;  // ty 0..7
  #pragma unroll
  for (int i = ty; i < 32; i += 8)
    tile[i][tx] = W[(long)(kb + i) * N + nb + tx];
  __syncthreads();
  #pragma unroll
  for (int i = ty; i < 32; i += 8)
    Wt[(long)(nb + i) * K + kb + tx] = (__bf16)tile[tx][i];
}

// ---------------------------------------------------------------------------
// 256x256 8-phase bf16 MFMA GEMM (T2+T3+T4+T5). Used for the qkv GEMM.
// C(MxN) = A(MxK) @ Bt(NxK)^T. BK=64, 512 threads = 8 waves (2M x 4N),
// per-wave output 128x64 (acc[8][4] 16x16 frags), LDS 128 KiB (2-deep dbuf).
//
// Staging: per K-tile, 8 slices of 64 rows x 64 cols (A0..A3, B0..B3); each
// slice = 1 global_load_lds_dwordx4 per wave. LDS dest linear; chunk XOR
// swizzle (stored chunk s at row r holds logical s^(r&7)) applied by
// pre-swizzling the per-lane GLOBAL source (both-sides swizzle, rule #21).
//
// Schedule (tile t computes buf[t&1], stages t+1 -> buf[~t&1]).
// R2 lesson: SPREAD the 8 staging loads 2-per-phase (burst-issue at ph1
// regressed 164->192 us). bf01/bf23 retained in regs (ph4 has no ds_reads).
//   ph1: read af-lo(8)+bf01(4) | stage B0,B1(t+1)
//   ph2: read bf23(4)          | stage B2,B3(t+1), vmcnt(4) [retire A1,A3(t)]
//   ph3: read af-hi(8)         | stage A0,A2(t+1)
//   ph4: no reads              | stage A1,A3(t+1), vmcnt(2) [retire B0-3,A0,A2]
// Invariant entering each tile: only A1,A3(t) in flight. vmcnt never 0 in
// main loop; last tile drains at ph2.
//
// Block swizzle: flat&7 = XCD owns a contiguous y-strip; needs (M/256)%8==0.
// mode 0: split bf16 epilogue (cols<768 -> C0 stride 768; else C1 stride 1536)
// mode 1: fp32 + bias epilogue into C0 stride N.
// ---------------------------------------------------------------------------
__global__ __launch_bounds__(512, 2) void gemm256_kernel(
    const __bf16* __restrict__ A, const __bf16* __restrict__ Bt,
    void* __restrict__ C0, void* __restrict__ C1,
    const float* __restrict__ bias,
    int M, int N, int K, int nxb, int mode) {
  __shared__ __bf16 As[2][256 * 64];   // 64 KB
  __shared__ __bf16 Bs[2][256 * 64];   // 64 KB
  const int tid = threadIdx.x;
  const int wave = tid >> 6, lane = tid & 63;

  const int flat = blockIdx.x;
  const int xcd = flat & 7, rem = flat >> 3;
  const int per = (M >> 8) >> 3;           // y-tiles per XCD
  const int yb = xcd * per + rem / nxb;
  const int xb = rem % nxb;
  const long m0 = (long)yb * 256;
  const int n0 = xb * 256;

  const int wm = (wave >> 2) * 128;        // M-half of this wave
  const int wn = (wave & 3) * 64;          // N-quarter of this wave

  // staging: wave covers rows [wave*8, wave*8+8) of each 64-row slice.
  const int srow = lane >> 3;              // 0..7 == row&7
  const int gchunk = (lane & 7) ^ srow;
  const __bf16* Ag = A + (m0 + wave * 8 + srow) * (long)K + gchunk * 8;
  const __bf16* Bg = Bt + ((long)n0 + wave * 8 + srow) * (long)K + gchunk * 8;
  const long slabK = 64 * (long)K;         // global elems between slices

  const int fr = lane & 15, qh = lane >> 4;
  const int c0 = ((qh ^ (fr & 7)) << 3);        // stored-chunk offset, kk=0
  const int c1 = (((qh + 4) ^ (fr & 7)) << 3);  // stored-chunk offset, kk=1

  floatx4 acc[8][4] = {};
  bf16x8 afl[4][2], bf01[2][2], bf23[2][2];
  const int nt = K >> 6;

  // prologue: stage tile 0; order B0..B3, A0, A2, A1, A3 (A1,A3 newest)
  {
    char* al = (char*)&As[0][0] + wave * 1024;
    char* bl = (char*)&Bs[0][0] + wave * 1024;
    gld16(Bg + 0 * slabK, bl + 0 * 8192);
    gld16(Bg + 1 * slabK, bl + 1 * 8192);
    gld16(Bg + 2 * slabK, bl + 2 * 8192);
    gld16(Bg + 3 * slabK, bl + 3 * 8192);
    gld16(Ag + 0 * slabK, al + 0 * 8192);
    gld16(Ag + 2 * slabK, al + 2 * 8192);
    gld16(Ag + 1 * slabK, al + 1 * 8192);
    gld16(Ag + 3 * slabK, al + 3 * 8192);
  }
  asm volatile("s_waitcnt vmcnt(2)" ::: "memory");  // A1,A3 stay in flight
  BARRIER();

  for (int t = 0; t < nt; ++t) {
    const int cur = t & 1;
    const bool pf = (t + 1 < nt);
    const __bf16* Ac = &As[cur][0];
    const __bf16* Bc = &Bs[cur][0];
    const __bf16* an = Ag + (t + 1) * 64;
    const __bf16* bn = Bg + (t + 1) * 64;
    char* al = (char*)&As[cur ^ 1][0] + wave * 1024;
    char* bl = (char*)&Bs[cur ^ 1][0] + wave * 1024;

    // ---- phase 1: (m-lo x n01); stage B0,B1 ------------------------------
    #pragma unroll
    for (int i = 0; i < 4; ++i) {
      const __bf16* p = &Ac[(wm + i * 16 + fr) * 64];
      afl[i][0] = *(const bf16x8*)(p + c0);
      afl[i][1] = *(const bf16x8*)(p + c1);
    }
    #pragma unroll
    for (int j = 0; j < 2; ++j) {
      const __bf16* p = &Bc[(wn + j * 16 + fr) * 64];
      bf01[j][0] = *(const bf16x8*)(p + c0);
      bf01[j][1] = *(const bf16x8*)(p + c1);
    }
    if (pf) { gld16(bn + 0 * slabK, bl + 0 * 8192);
              gld16(bn + 1 * slabK, bl + 1 * 8192); }
    BARRIER();
    asm volatile("s_waitcnt lgkmcnt(0)");
    __builtin_amdgcn_sched_barrier(0);
    __builtin_amdgcn_s_setprio(1);
    #pragma unroll
    for (int i = 0; i < 4; ++i)
      #pragma unroll
      for (int j = 0; j < 2; ++j) {
        acc[i][j] = MFMA16(afl[i][0], bf01[j][0], acc[i][j]);
        acc[i][j] = MFMA16(afl[i][1], bf01[j][1], acc[i][j]);
      }
    __builtin_amdgcn_s_setprio(0);
    BARRIER();

    // ---- phase 2: (m-lo x n23); stage B2,B3; retire A1,A3(t) -------------
    #pragma unroll
    for (int j = 0; j < 2; ++j) {
      const __bf16* p = &Bc[(wn + (2 + j) * 16 + fr) * 64];
      bf23[j][0] = *(const bf16x8*)(p + c0);
      bf23[j][1] = *(const bf16x8*)(p + c1);
    }
    if (pf) {
      gld16(bn + 2 * slabK, bl + 2 * 8192);
      gld16(bn + 3 * slabK, bl + 3 * 8192);
      asm volatile("s_waitcnt vmcnt(4)" ::: "memory");
    } else {
      asm volatile("s_waitcnt vmcnt(0)" ::: "memory");  // last tile: drain
    }
    BARRIER();
    asm volatile("s_waitcnt lgkmcnt(0)");
    __builtin_amdgcn_sched_barrier(0);
    __builtin_amdgcn_s_setprio(1);
    #pragma unroll
    for (int i = 0; i < 4; ++i)
      #pragma unroll
      for (int j = 0; j < 2; ++j) {
        acc[i][2 + j] = MFMA16(afl[i][0], bf23[j][0], acc[i][2 + j]);
        acc[i][2 + j] = MFMA16(afl[i][1], bf23[j][1], acc[i][2 + j]);
      }
    __builtin_amdgcn_s_setprio(0);
    BARRIER();

    // ---- phase 3: (m-hi x n23), bf23 in regs; stage A0,A2 ----------------
    #pragma unroll
    for (int i = 0; i < 4; ++i) {
      const __bf16* p = &Ac[(wm + (4 + i) * 16 + fr) * 64];
      afl[i][0] = *(const bf16x8*)(p + c0);
      afl[i][1] = *(const bf16x8*)(p + c1);
    }
    if (pf) { gld16(an + 0 * slabK, al + 0 * 8192);
              gld16(an + 2 * slabK, al + 2 * 8192); }
    BARRIER();
    asm volatile("s_waitcnt lgkmcnt(0)");
    __builtin_amdgcn_sched_barrier(0);
    __builtin_amdgcn_s_setprio(1);
    #pragma unroll
    for (int i = 0; i < 4; ++i)
      #pragma unroll
      for (int j = 0; j < 2; ++j) {
        acc[4 + i][2 + j] = MFMA16(afl[i][0], bf23[j][0], acc[4 + i][2 + j]);
        acc[4 + i][2 + j] = MFMA16(afl[i][1], bf23[j][1], acc[4 + i][2 + j]);
      }
    __builtin_amdgcn_s_setprio(0);
    BARRIER();

    // ---- phase 4: (m-hi x n01), bf01 in regs; stage A1,A3; retire 6 ------
    if (pf) {
      gld16(an + 1 * slabK, al + 1 * 8192);
      gld16(an + 3 * slabK, al + 3 * 8192);
      asm volatile("s_waitcnt vmcnt(2)" ::: "memory");  // B0-3,A0,A2(t+1) in
    }
    BARRIER();
    asm volatile("s_waitcnt lgkmcnt(0)");
    __builtin_amdgcn_sched_barrier(0);
    __builtin_amdgcn_s_setprio(1);
    #pragma unroll
    for (int i = 0; i < 4; ++i)
      #pragma unroll
      for (int j = 0; j < 2; ++j) {
        acc[4 + i][j] = MFMA16(afl[i][0], bf01[j][0], acc[4 + i][j]);
        acc[4 + i][j] = MFMA16(afl[i][1], bf01[j][1], acc[4 + i][j]);
      }
    __builtin_amdgcn_s_setprio(0);
    BARRIER();
  }

  // epilogue
  const int col = lane & 15, rq = (lane >> 4) * 4;
  if (mode == 1) {
    #pragma unroll
    for (int j = 0; j < 4; ++j) {
      const int gn = n0 + wn + j * 16 + col;
      const float bj = bias[gn];
      #pragma unroll
      for (int i = 0; i < 8; ++i)
        #pragma unroll
        for (int r = 0; r < 4; ++r)
          ((float*)C0)[(m0 + wm + i * 16 + rq + r) * (long)N + gn] =
              acc[i][j][r] + bj;
    }
  } else if (n0 + 256 <= CDIM) {  // whole block in q half (n0 in {0,256,512})
    #pragma unroll
    for (int j = 0; j < 4; ++j) {
      const int gn = n0 + wn + j * 16 + col;
      #pragma unroll
      for (int i = 0; i < 8; ++i)
        #pragma unroll
        for (int r = 0; r < 4; ++r)
          ((__bf16*)C0)[(m0 + wm + i * 16 + rq + r) * (long)CDIM + gn] =
              (__bf16)acc[i][j][r];
    }
  } else {                        // kv half
    #pragma unroll
    for (int j = 0; j < 4; ++j) {
      const int gn = n0 + wn + j * 16 + col - CDIM;
      #pragma unroll
      for (int i = 0; i < 8; ++i)
        #pragma unroll
        for (int r = 0; r < 4; ++r)
          ((__bf16*)C1)[(m0 + wm + i * 16 + rq + r) * (long)EDIM + gn] =
              (__bf16)acc[i][j][r];
    }
  }
}

// ---------------------------------------------------------------------------
// 128x128 bf16 MFMA GEMM (m97 structure). Used for the proj GEMM (better
// grid packing: 256-thread blocks, 32 KB LDS -> ~2-3 blocks/CU).
// mode 1: fp32 + bias epilogue into C0 stride N.
// ---------------------------------------------------------------------------
__global__ __launch_bounds__(256) void gemm_glds_kernel(
    const __bf16* __restrict__ A, const __bf16* __restrict__ Bt,
    void* __restrict__ C0, void* __restrict__ C1,
    const float* __restrict__ bias,
    int M, int N, int K, int nxb, int mode) {
  __shared__ __bf16 As[128 * 32];
  __shared__ __bf16 Bs[128 * 32];
  const int tid = threadIdx.x;
  const int wave = tid >> 6, lane = tid & 63;

  const int flat = blockIdx.x;
  const int xcd = flat & 7, rem = flat >> 3;
  const int per = (M >> 7) >> 3;           // y-tiles per XCD
  const int yb = xcd * per + rem / nxb;
  const int xb = rem % nxb;
  const long m0 = (long)yb * 128;
  const int n0 = xb * 128;

  const int wm = (wave >> 1) * 64, wn = (wave & 1) * 64;

  const int srow = lane >> 2;
  const int gchunk = (lane & 3) ^ ((lane >> 3) & 3);
  const __bf16* Ag = A + (m0 + wave * 16 + srow) * (long)K + gchunk * 8;
  const __bf16* Bg = Bt + ((long)n0 + wave * 16 + srow) * (long)K + gchunk * 8;
  char* Al = (char*)As + wave * 16 * 64;   // + lane*16 applied by HW
  char* Bl = (char*)Bs + wave * 16 * 64;
  const long rowskip = 64 * (long)K;

  const int fr = lane & 15;
  const int csw = ((lane >> 4) ^ ((fr >> 1) & 3)) * 8;  // swizzled k-chunk

  floatx4 acc[4][4] = {};

  for (int k0 = 0; k0 < K; k0 += 32) {
    __syncthreads();
    gld16(Ag + k0, Al);
    gld16(Ag + k0 + rowskip, Al + 64 * 64);
    gld16(Bg + k0, Bl);
    gld16(Bg + k0 + rowskip, Bl + 64 * 64);
    __syncthreads();   // compiler drains vmcnt before s_barrier
    bf16x8 af[4], bfr[4];
    #pragma unroll
    for (int i = 0; i < 4; ++i)
      af[i] = *(const bf16x8*)&As[(wm + i * 16 + fr) * 32 + csw];
    #pragma unroll
    for (int j = 0; j < 4; ++j)
      bfr[j] = *(const bf16x8*)&Bs[(wn + j * 16 + fr) * 32 + csw];
    #pragma unroll
    for (int i = 0; i < 4; ++i)
      #pragma unroll
      for (int j = 0; j < 4; ++j)
        acc[i][j] = __builtin_amdgcn_mfma_f32_16x16x32_bf16(af[i], bfr[j], acc[i][j], 0, 0, 0);
  }

  const int col = lane & 15, rq = (lane >> 4) * 4;
  if (mode == 1) {
    #pragma unroll
    for (int i = 0; i < 4; ++i)
      #pragma unroll
      for (int j = 0; j < 4; ++j)
        #pragma unroll
        for (int r = 0; r < 4; ++r) {
          long gm = m0 + wm + i * 16 + rq + r;
          int gn = n0 + wn + j * 16 + col;
          ((float*)C0)[gm * N + gn] = acc[i][j][r] + bias[gn];
        }
  } else {
    if (n0 + 128 <= CDIM) {
      #pragma unroll
      for (int i = 0; i < 4; ++i)
        #pragma unroll
        for (int j = 0; j < 4; ++j)
          #pragma unroll
          for (int r = 0; r < 4; ++r) {
            long gm = m0 + wm + i * 16 + rq + r;
            int gn = n0 + wn + j * 16 + col;
            ((__bf16*)C0)[gm * CDIM + gn] = (__bf16)acc[i][j][r];
          }
    } else {
      #pragma unroll
      for (int i = 0; i < 4; ++i)
        #pragma unroll
        for (int j = 0; j < 4; ++j)
          #pragma unroll
          for (int r = 0; r < 4; ++r) {
            long gm = m0 + wm + i * 16 + rq + r;
            int gn = n0 + wn + j * 16 + col - CDIM;
            ((__bf16*)C1)[gm * EDIM + gn] = (__bf16)acc[i][j][r];
          }
    }
  }
}

// ---------------------------------------------------------------------------
// ktv partials with FUSED softmax over head_dim:
// ktv_part[split][b][h][d][e] = sum_{n in split} softmax(k[b,n,h,:])[d]*v[b,n,h,e]
// grid: (4, NHEADS, NB), block 256 (4 waves, each 16 d-rows x 64 e-cols).
// Softmax: the 8 lanes sharing a k-row (sn) hold its 64 values (8 each);
// 3-step shfl_xor max/sum within the 8-lane group, then normalize.
// ---------------------------------------------------------------------------
__global__ __launch_bounds__(256) void ktv_kernel(
    const __bf16* __restrict__ kv, float* __restrict__ ktv_part) {
  const int split = blockIdx.x, h = blockIdx.y, b = blockIdx.z;
  __shared__ __bf16 As[64 * 40];  // [d][n_local]
  __shared__ __bf16 Bs[64 * 40];  // [e][n_local]
  const int tid = threadIdx.x, wave = tid >> 6, lane = tid & 63;
  const int sn = tid >> 3;        // 0..31
  const int sc = (tid & 7) * 8;   // 0..56
  const int fr = lane & 15, fk = (lane >> 4) * 8;
  floatx4 acc[4] = {};
  const long rowbase = (long)b * NTOK * EDIM;

  for (int n0 = split * 1024; n0 < split * 1024 + 1024; n0 += 32) {
    __syncthreads();
    const __bf16* krow = kv + rowbase + (long)(n0 + sn) * EDIM + h * HD + sc;
    const __bf16* vrow = krow + CDIM;
    uint4 ku = *(const uint4*)krow;
    uint4 vu = *(const uint4*)vrow;
    const __bf16* kh = (const __bf16*)&ku;
    const __bf16* vh = (const __bf16*)&vu;
    // fused softmax over this row's 64 k values (8 lanes x 8 elems)
    float kf[8];
    float mx = -1e30f;
    #pragma unroll
    for (int j = 0; j < 8; ++j) { kf[j] = (float)kh[j]; mx = fmaxf(mx, kf[j]); }
    #pragma unroll
    for (int m = 1; m < 8; m <<= 1) mx = fmaxf(mx, __shfl_xor(mx, m));
    float s = 0.f;
    #pragma unroll
    for (int j = 0; j < 8; ++j) { kf[j] = __expf(kf[j] - mx); s += kf[j]; }
    #pragma unroll
    for (int m = 1; m < 8; m <<= 1) s += __shfl_xor(s, m);
    const float inv = 1.f / s;
    #pragma unroll
    for (int j = 0; j < 8; ++j) {
      As[(sc + j) * 40 + sn] = (__bf16)(kf[j] * inv);
      Bs[(sc + j) * 40 + sn] = vh[j];
    }
    __syncthreads();
    bf16x8 af = *(const bf16x8*)&As[(wave * 16 + fr) * 40 + fk];
    #pragma unroll
    for (int j = 0; j < 4; ++j) {
      bf16x8 bf_ = *(const bf16x8*)&Bs[(j * 16 + fr) * 40 + fk];
      acc[j] = __builtin_amdgcn_mfma_f32_16x16x32_bf16(af, bf_, acc[j], 0, 0, 0);
    }
  }

  const int col = lane & 15, rq = (lane >> 4) * 4;
  long base = (((long)split * NB + b) * NHEADS + h) * (HD * HD);
  #pragma unroll
  for (int j = 0; j < 4; ++j)
    #pragma unroll
    for (int r = 0; r < 4; ++r)
      ktv_part[base + (wave * 16 + rq + r) * HD + j * 16 + col] = acc[j][r];
}

// ---------------------------------------------------------------------------
// Build expanded ektv TRANSPOSED (bf16, [b][H][e][d], H in [0,24)) from the
// 4 partials, applying the head-expansion roll on the flattened (h*64+e)
// axis. Transposed layout makes attn's B-stage fully coalesced (the old
// [d][e] layout forced 16 scalar strided global reads per attn thread).
// Writes here are scattered 2B (stride 128B across threads) but the buffer
// is 786 KB / L2-resident and this kernel is tiny.
// ---------------------------------------------------------------------------
__global__ __launch_bounds__(256) void ektv_kernel(
    const float* __restrict__ ktv_part, __bf16* __restrict__ ektv) {
  int idx = blockIdx.x * 256 + threadIdx.x;  // < 8*24*64*64 = 786432
  int e = idx & 63;
  int d = (idx >> 6) & 63;
  int H = (idx >> 12) % 24;
  int b = idx / 98304;
  int c = H * 64 + e;
  int cp = (c < CDIM) ? c : (c - CDIM + 32) % CDIM;
  int hs = cp >> 6, es = cp & 63;
  long o = (((long)b * NHEADS + hs) * HD + d) * HD + es;
  float s = 0.f;
  #pragma unroll
  for (int sp = 0; sp < 4; ++sp)
    s += ktv_part[(long)sp * (NB * NHEADS * HD * HD) + o];
  // transposed output: [b][H][e][d]
  long ob = ((long)(idx >> 12)) * (HD * HD) + (long)e * HD + d;
  ektv[ob] = (__bf16)s;
}

// ---------------------------------------------------------------------------
// attn: mid[b, n, H*64+e] = scale * sum_d eq[b,H,n,d] * ektv_t[b,H,e,d]
// eq columns for head H are q columns (qbase..qbase+63) mod 768.
// grid: (NTOK/128, 24, NB), block 256 (4 waves x 32 token rows).
// B-stage is now a straight coalesced copy (ektv pre-transposed).
// ---------------------------------------------------------------------------
__global__ __launch_bounds__(256) void attn_kernel(
    const __bf16* __restrict__ q, const __bf16* __restrict__ ektv,
    __bf16* __restrict__ mid) {
  const int tt = blockIdx.x, H = blockIdx.y, b = blockIdx.z;
  __shared__ __bf16 As[128 * 72];  // [n_local][d]
  __shared__ __bf16 Bs[64 * 72];   // [e][d]
  const int tid = threadIdx.x, wave = tid >> 6, lane = tid & 63;
  const int qbase = (H < NHEADS) ? H * 64 : (H - NHEADS) * 64 + 32;
  const long n0 = (long)b * NTOK + tt * 128;

  {  // stage A (q slice, handling the circular roll per 8-wide chunk)
    int nl = tid >> 1, d0 = (tid & 1) * 32;
    const __bf16* qrow = q + (n0 + nl) * CDIM;
    #pragma unroll
    for (int cch = 0; cch < 4; ++cch) {
      int d = d0 + cch * 8;
      int c0 = qbase + d;
      if (c0 >= CDIM) c0 -= CDIM;
      *(uint4*)&As[nl * 72 + d] = *(const uint4*)(qrow + c0);
    }
  }
  {  // stage B: Bs[e][d] = ektv_t[b][H][e][d] (coalesced 16B copies)
    int e = tid >> 2, ch4 = (tid & 3) * 8;  // 2 chunks per thread
    const __bf16* src = ektv + ((long)b * 24 + H) * (HD * HD) + e * HD;
    *(uint4*)&Bs[e * 72 + ch4] = *(const uint4*)(src + ch4);
    *(uint4*)&Bs[e * 72 + ch4 + 32] = *(const uint4*)(src + ch4 + 32);
  }
  __syncthreads();

  floatx4 acc[2][4] = {};
  const int fr = lane & 15, fk = (lane >> 4) * 8;
  const int wm = wave * 32;
  #pragma unroll
  for (int kk = 0; kk < 64; kk += 32) {
    bf16x8 af0 = *(const bf16x8*)&As[(wm + fr) * 72 + kk + fk];
    bf16x8 af1 = *(const bf16x8*)&As[(wm + 16 + fr) * 72 + kk + fk];
    #pragma unroll
    for (int j = 0; j < 4; ++j) {
      bf16x8 bf_ = *(const bf16x8*)&Bs[(j * 16 + fr) * 72 + kk + fk];
      acc[0][j] = __builtin_amdgcn_mfma_f32_16x16x32_bf16(af0, bf_, acc[0][j], 0, 0, 0);
      acc[1][j] = __builtin_amdgcn_mfma_f32_16x16x32_bf16(af1, bf_, acc[1][j], 0, 0, 0);
    }
  }

  const int col = lane & 15, rq = (lane >> 4) * 4;
  const float scale = 0.125f;  // HEAD_DIM^-0.5
  #pragma unroll
  for (int i = 0; i < 2; ++i)
    #pragma unroll
    for (int j = 0; j < 4; ++j)
      #pragma unroll
      for (int r = 0; r < 4; ++r) {
        long n = n0 + wm + i * 16 + rq + r;
        mid[n * EDIM + H * 64 + j * 16 + col] = (__bf16)(acc[i][j][r] * scale);
      }
}

// ---------------------------------------------------------------------------
// LePE depthwise 3x3 conv, tiled through LDS, sliding-window register reuse.
// grid: (12 ch-groups of 64 q-channels, 16 y-groups of 4 rows, NB).
// ---------------------------------------------------------------------------
__global__ __launch_bounds__(256) void lepe_kernel(
    const __bf16* __restrict__ q, const float* __restrict__ w_lepe,
    const float* __restrict__ b_lepe, __bf16* __restrict__ mid) {
  __shared__ __bf16 smem[6 * 64 * 64];  // [row][x][ch], 48 KB
  const int g = blockIdx.x, yg = blockIdx.y, b = blockIdx.z;
  const int y0 = yg * 4;
  const int tid = threadIdx.x;

  #pragma unroll
  for (int k = 0; k < 12; ++k) {
    int v = tid + k * 256;            // 0..3071
    int r = v >> 9;                   // row in slab, 0..5
    int rem = v & 511;
    int x = rem >> 3;
    int chv = (rem & 7) * 8;
    int yy = y0 + r - 1;
    uint4 val = {0u, 0u, 0u, 0u};
    if (yy >= 0 && yy < 64)
      val = *(const uint4*)(q + ((long)(b * NTOK + yy * 64 + x)) * CDIM + g * 64 + chv);
    *(uint4*)&smem[r * 4096 + x * 64 + chv] = val;
  }
  __syncthreads();

  const int ch = tid & 63, xg = tid >> 6;
  const int cq = g * 64 + ch;                 // expanded channel (identity half)
  const int c2 = CDIM + ((cq + 736) % CDIM);  // rolled duplicate channel
  float w1[9], w2[9];
  #pragma unroll
  for (int j = 0; j < 9; ++j) {
    w1[j] = w_lepe[cq * 9 + j];
    w2[j] = w_lepe[c2 * 9 + j];
  }
  const float bias1 = b_lepe[cq], bias2 = b_lepe[c2];

  const int x0 = xg * 16;
  float cm[6], cc[6], cp[6];
  #pragma unroll
  for (int r = 0; r < 6; ++r) {
    cm[r] = (x0 > 0) ? (float)smem[r * 4096 + (x0 - 1) * 64 + ch] : 0.f;  // wave-uniform cond
    cc[r] = (float)smem[r * 4096 + x0 * 64 + ch];
  }
  #pragma unroll
  for (int i = 0; i < 16; ++i) {
    const int x = x0 + i;
    #pragma unroll
    for (int r = 0; r < 6; ++r)
      cp[r] = (x < 63) ? (float)smem[r * 4096 + (x + 1) * 64 + ch] : 0.f;  // wave-uniform
    #pragma unroll
    for (int ly = 0; ly < 4; ++ly) {
      float a1 = bias1, a2 = bias2;
      #pragma unroll
      for (int r = 0; r < 3; ++r) {
        const float vm = cm[ly + r], vc = cc[ly + r], vp = cp[ly + r];
        a1 += w1[r * 3 + 0] * vm + w1[r * 3 + 1] * vc + w1[r * 3 + 2] * vp;
        a2 += w2[r * 3 + 0] * vm + w2[r * 3 + 1] * vc + w2[r * 3 + 2] * vp;
      }
      long o = ((long)(b * NTOK + (y0 + ly) * 64 + x)) * EDIM;
      mid[o + cq] = (__bf16)((float)mid[o + cq] + a1);
      mid[o + c2] = (__bf16)((float)mid[o + c2] + a2);
    }
    #pragma unroll
    for (int r = 0; r < 6; ++r) { cm[r] = cc[r]; cc[r] = cp[r]; }
  }
}

// ---------------------------------------------------------------------------
// launch
// ---------------------------------------------------------------------------
extern "C" void kernel_launch(void* const* d_in, const int* in_sizes, int n_in,
                              void* d_out, int out_size, void* d_ws, size_t ws_size,
                              hipStream_t stream) {
  const float* x      = (const float*)d_in[0];
  const float* w_q    = (const float*)d_in[1];
  const float* w_kv   = (const float*)d_in[2];
  const float* w_proj = (const float*)d_in[3];
  const float* b_proj = (const float*)d_in[4];
  const float* w_lepe = (const float*)d_in[5];
  const float* b_lepe = (const float*)d_in[6];
  float* out = (float*)d_out;

  char* ws = (char*)d_ws;
  __bf16* Wt_qkv = (__bf16*)ws; ws += (long)(CDIM + EDIM) * CDIM * 2;  // 2304x768 (NxK)
  __bf16* Wt_p   = (__bf16*)ws; ws += (long)CDIM * EDIM * 2;           // 768x1536 (NxK)
  __bf16* xb     = (__bf16*)ws; ws += (long)TOTTOK * CDIM * 2;
  __bf16* qb     = (__bf16*)ws; ws += (long)TOTTOK * CDIM * 2;
  __bf16* kvb    = (__bf16*)ws; ws += (long)TOTTOK * EDIM * 2;         // later aliased as mid
  float*  ktv_part = (float*)ws; ws += (long)4 * NB * NHEADS * HD * HD * 4;
  __bf16* ektv   = (__bf16*)ws; ws += (long)NB * 24 * HD * HD * 2;
  __bf16* mid = kvb;  // alias: kv is dead once ektv is built

  // 1. x -> bf16
  f32_to_bf16_kernel<<<(TOTTOK * CDIM) / (256 * 4), 256, 0, stream>>>(
      x, xb, (long)TOTTOK * CDIM);
  // 2. weight transposes (K x N fp32 -> N x K bf16), q|kv concatenated
  transpose_w_kernel<<<dim3(CDIM / 32, CDIM / 32), 256, 0, stream>>>(
      w_q, Wt_qkv, CDIM, CDIM);
  transpose_w_kernel<<<dim3(EDIM / 32, CDIM / 32), 256, 0, stream>>>(
      w_kv, Wt_qkv + (long)CDIM * CDIM, CDIM, EDIM);
  transpose_w_kernel<<<dim3(CDIM / 32, EDIM / 32), 256, 0, stream>>>(
      w_proj, Wt_p, EDIM, CDIM);
  // 3. fused qkv = x @ [w_q | w_kv]  (256^2 8-phase, split epilogue -> qb, kvb)
  //    grid: (32768/256) y-tiles * 9 x-tiles = 1152 blocks
  gemm256_kernel<<<(TOTTOK / 256) * 9, 512, 0, stream>>>(
      xb, Wt_qkv, qb, kvb, nullptr, TOTTOK, CDIM + EDIM, CDIM, 9, 0);
  // 4. ktv partials (softmax fused into staging; split-K over tokens)
  ktv_kernel<<<dim3(4, NHEADS, NB), 256, 0, stream>>>(kvb, ktv_part);
  // 5. reduce partials + head-expand -> ektv (TRANSPOSED [b][H][e][d])
  ektv_kernel<<<(NB * 24 * HD * HD) / 256, 256, 0, stream>>>(ktv_part, ektv);
  // 6. attn -> mid (overwrites kv buffer)
  attn_kernel<<<dim3(NTOK / 128, 24, NB), 256, 0, stream>>>(qb, ektv, mid);
  // 7. mid += lepe (tiled, LDS-staged, sliding-window)
  lepe_kernel<<<dim3(12, 16, NB), 256, 0, stream>>>(qb, w_lepe, b_lepe, mid);
  // 8. out = mid @ w_proj + b_proj (128^2 m97 structure: better packing)
  //    grid: 256 y-tiles * 6 x-tiles = 1536 blocks
  gemm_glds_kernel<<<(TOTTOK / 128) * 6, 256, 0, stream>>>(
      mid, Wt_p, out, nullptr, b_proj, TOTTOK, CDIM, EDIM, 6, 1);
}

// Round 4
// 595.901 us; speedup vs baseline: 1.1978x; 1.0539x over previous
//
#include <hip/hip_runtime.h>

// ---------------------------------------------------------------------------
// Problem constants: B=8, N=4096 (64x64 image), DIM=768, HEADS=12, HEAD_DIM=64
// EXP=2 -> EDIM=1536, expanded heads = 24.
// ---------------------------------------------------------------------------
#define NB 8
#define NTOK 4096
#define CDIM 768
#define EDIM 1536
#define NHEADS 12
#define HD 64
#define TOTTOK (NB * NTOK)          // 32768
#define KSPLIT 8

typedef float floatx4 __attribute__((ext_vector_type(4)));
typedef __bf16 bf16x8 __attribute__((ext_vector_type(8)));

// async 16B global -> LDS (lane-contiguous LDS dest: wave base + lane*16)
__device__ __forceinline__ void gld16(const __bf16* g, void* l) {
  __builtin_amdgcn_global_load_lds(
      (const __attribute__((address_space(1))) unsigned int*)g,
      (__attribute__((address_space(3))) unsigned int*)l, 16, 0, 0);
}

#define MFMA16(a, b, c) __builtin_amdgcn_mfma_f32_16x16x32_bf16(a, b, c, 0, 0, 0)
#define FENCE() asm volatile("" ::: "memory")
#define BARRIER() do { FENCE(); __builtin_amdgcn_s_barrier(); FENCE(); } while (0)

// ---------------------------------------------------------------------------
// fp32 -> bf16 elementwise convert (x)
// ---------------------------------------------------------------------------
__global__ __launch_bounds__(256) void f32_to_bf16_kernel(
    const float* __restrict__ in, __bf16* __restrict__ out, long n) {
  long i = ((long)blockIdx.x * 256 + threadIdx.x) * 4;
  if (i >= n) return;
  float4 f = *(const float4*)(in + i);
  alignas(8) __bf16 h[4];
  h[0] = (__bf16)f.x; h[1] = (__bf16)f.y; h[2] = (__bf16)f.z; h[3] = (__bf16)f.w;
  *(unsigned long long*)(out + i) = *(const unsigned long long*)h;
}

// ---------------------------------------------------------------------------
// W (K x N fp32, row-major) -> Wt (N x K bf16, row-major)
// grid: (N/32, K/32), block 256
// ---------------------------------------------------------------------------
__global__ __launch_bounds__(256) void transpose_w_kernel(
    const float* __restrict__ W, __bf16* __restrict__ Wt, int K, int N) {
  __shared__ float tile[32][33];
  int nb = blockIdx.x * 32, kb = blockIdx.y * 32;
  int tx = threadIdx.x & 31, ty = threadIdx.x >> 5;  // ty 0..7
  #pragma unroll
  for (int i = ty; i < 32; i += 8)
    tile[i][tx] = W[(long)(kb + i) * N + nb + tx];
  __syncthreads();
  #pragma unroll
  for (int i = ty; i < 32; i += 8)
    Wt[(long)(nb + i) * K + kb + tx] = (__bf16)tile[tx][i];
}

// ---------------------------------------------------------------------------
// 256x256 8-phase bf16 MFMA GEMM (T2+T3+T4+T5). Used for the qkv GEMM.
// C(MxN) = A(MxK) @ Bt(NxK)^T. BK=64, 512 threads = 8 waves (2M x 4N),
// per-wave output 128x64 (acc[8][4] 16x16 frags), LDS 128 KiB (2-deep dbuf).
//
// Staging: per K-tile, 8 slices of 64 rows x 64 cols (A0..A3, B0..B3); each
// slice = 1 global_load_lds_dwordx4 per wave. LDS dest linear; chunk XOR
// swizzle (stored chunk s at row r holds logical s^(r&7)) applied by
// pre-swizzling the per-lane GLOBAL source (both-sides swizzle, rule #21).
//
// Schedule (tile t computes buf[t&1], stages t+1 -> buf[~t&1]).
// R2 lesson: SPREAD the 8 staging loads 2-per-phase (burst-issue at ph1
// regressed 164->192 us). bf01/bf23 retained in regs (ph4 has no ds_reads).
//   ph1: read af-lo(8)+bf01(4) | stage B0,B1(t+1)
//   ph2: read bf23(4)          | stage B2,B3(t+1), vmcnt(4) [retire A1,A3(t)]
//   ph3: read af-hi(8)         | stage A0,A2(t+1)
//   ph4: no reads              | stage A1,A3(t+1), vmcnt(2) [retire B0-3,A0,A2]
// Invariant entering each tile: only A1,A3(t) in flight. vmcnt never 0 in
// main loop; last tile drains at ph2.
//
// R4: mode-0 epilogue via wave-private LDS bounce (16x76 bf16 scratch):
// 128 scalar 2B stores/thread -> 16 uint4 stores/thread; kills the 1.45x
// partial-line write amplification (WRITE_SIZE 217 MB vs 150 logical).
//
// Block swizzle: flat&7 = XCD owns a contiguous y-strip; needs (M/256)%8==0.
// mode 0: split bf16 epilogue (cols<768 -> C0 stride 768; else C1 stride 1536)
// mode 1: fp32 + bias epilogue into C0 stride N.
// ---------------------------------------------------------------------------
__global__ __launch_bounds__(512, 2) void gemm256_kernel(
    const __bf16* __restrict__ A, const __bf16* __restrict__ Bt,
    void* __restrict__ C0, void* __restrict__ C1,
    const float* __restrict__ bias,
    int M, int N, int K, int nxb, int mode) {
  __shared__ __bf16 As[2][256 * 64];   // 64 KB
  __shared__ __bf16 Bs[2][256 * 64];   // 64 KB
  const int tid = threadIdx.x;
  const int wave = tid >> 6, lane = tid & 63;

  const int flat = blockIdx.x;
  const int xcd = flat & 7, rem = flat >> 3;
  const int per = (M >> 8) >> 3;           // y-tiles per XCD
  const int yb = xcd * per + rem / nxb;
  const int xb = rem % nxb;
  const long m0 = (long)yb * 256;
  const int n0 = xb * 256;

  const int wm = (wave >> 2) * 128;        // M-half of this wave
  const int wn = (wave & 3) * 64;          // N-quarter of this wave

  // staging: wave covers rows [wave*8, wave*8+8) of each 64-row slice.
  const int srow = lane >> 3;              // 0..7 == row&7
  const int gchunk = (lane & 7) ^ srow;
  const __bf16* Ag = A + (m0 + wave * 8 + srow) * (long)K + gchunk * 8;
  const __bf16* Bg = Bt + ((long)n0 + wave * 8 + srow) * (long)K + gchunk * 8;
  const long slabK = 64 * (long)K;         // global elems between slices

  const int fr = lane & 15, qh = lane >> 4;
  const int c0 = ((qh ^ (fr & 7)) << 3);        // stored-chunk offset, kk=0
  const int c1 = (((qh + 4) ^ (fr & 7)) << 3);  // stored-chunk offset, kk=1

  floatx4 acc[8][4] = {};
  bf16x8 afl[4][2], bf01[2][2], bf23[2][2];
  const int nt = K >> 6;

  // prologue: stage tile 0; order B0..B3, A0, A2, A1, A3 (A1,A3 newest)
  {
    char* al = (char*)&As[0][0] + wave * 1024;
    char* bl = (char*)&Bs[0][0] + wave * 1024;
    gld16(Bg + 0 * slabK, bl + 0 * 8192);
    gld16(Bg + 1 * slabK, bl + 1 * 8192);
    gld16(Bg + 2 * slabK, bl + 2 * 8192);
    gld16(Bg + 3 * slabK, bl + 3 * 8192);
    gld16(Ag + 0 * slabK, al + 0 * 8192);
    gld16(Ag + 2 * slabK, al + 2 * 8192);
    gld16(Ag + 1 * slabK, al + 1 * 8192);
    gld16(Ag + 3 * slabK, al + 3 * 8192);
  }
  asm volatile("s_waitcnt vmcnt(2)" ::: "memory");  // A1,A3 stay in flight
  BARRIER();

  for (int t = 0; t < nt; ++t) {
    const int cur = t & 1;
    const bool pf = (t + 1 < nt);
    const __bf16* Ac = &As[cur][0];
    const __bf16* Bc = &Bs[cur][0];
    const __bf16* an = Ag + (t + 1) * 64;
    const __bf16* bn = Bg + (t + 1) * 64;
    char* al = (char*)&As[cur ^ 1][0] + wave * 1024;
    char* bl = (char*)&Bs[cur ^ 1][0] + wave * 1024;

    // ---- phase 1: (m-lo x n01); stage B0,B1 ------------------------------
    #pragma unroll
    for (int i = 0; i < 4; ++i) {
      const __bf16* p = &Ac[(wm + i * 16 + fr) * 64];
      afl[i][0] = *(const bf16x8*)(p + c0);
      afl[i][1] = *(const bf16x8*)(p + c1);
    }
    #pragma unroll
    for (int j = 0; j < 2; ++j) {
      const __bf16* p = &Bc[(wn + j * 16 + fr) * 64];
      bf01[j][0] = *(const bf16x8*)(p + c0);
      bf01[j][1] = *(const bf16x8*)(p + c1);
    }
    if (pf) { gld16(bn + 0 * slabK, bl + 0 * 8192);
              gld16(bn + 1 * slabK, bl + 1 * 8192); }
    BARRIER();
    asm volatile("s_waitcnt lgkmcnt(0)");
    __builtin_amdgcn_sched_barrier(0);
    __builtin_amdgcn_s_setprio(1);
    #pragma unroll
    for (int i = 0; i < 4; ++i)
      #pragma unroll
      for (int j = 0; j < 2; ++j) {
        acc[i][j] = MFMA16(afl[i][0], bf01[j][0], acc[i][j]);
        acc[i][j] = MFMA16(afl[i][1], bf01[j][1], acc[i][j]);
      }
    __builtin_amdgcn_s_setprio(0);
    BARRIER();

    // ---- phase 2: (m-lo x n23); stage B2,B3; retire A1,A3(t) -------------
    #pragma unroll
    for (int j = 0; j < 2; ++j) {
      const __bf16* p = &Bc[(wn + (2 + j) * 16 + fr) * 64];
      bf23[j][0] = *(const bf16x8*)(p + c0);
      bf23[j][1] = *(const bf16x8*)(p + c1);
    }
    if (pf) {
      gld16(bn + 2 * slabK, bl + 2 * 8192);
      gld16(bn + 3 * slabK, bl + 3 * 8192);
      asm volatile("s_waitcnt vmcnt(4)" ::: "memory");
    } else {
      asm volatile("s_waitcnt vmcnt(0)" ::: "memory");  // last tile: drain
    }
    BARRIER();
    asm volatile("s_waitcnt lgkmcnt(0)");
    __builtin_amdgcn_sched_barrier(0);
    __builtin_amdgcn_s_setprio(1);
    #pragma unroll
    for (int i = 0; i < 4; ++i)
      #pragma unroll
      for (int j = 0; j < 2; ++j) {
        acc[i][2 + j] = MFMA16(afl[i][0], bf23[j][0], acc[i][2 + j]);
        acc[i][2 + j] = MFMA16(afl[i][1], bf23[j][1], acc[i][2 + j]);
      }
    __builtin_amdgcn_s_setprio(0);
    BARRIER();

    // ---- phase 3: (m-hi x n23), bf23 in regs; stage A0,A2 ----------------
    #pragma unroll
    for (int i = 0; i < 4; ++i) {
      const __bf16* p = &Ac[(wm + (4 + i) * 16 + fr) * 64];
      afl[i][0] = *(const bf16x8*)(p + c0);
      afl[i][1] = *(const bf16x8*)(p + c1);
    }
    if (pf) { gld16(an + 0 * slabK, al + 0 * 8192);
              gld16(an + 2 * slabK, al + 2 * 8192); }
    BARRIER();
    asm volatile("s_waitcnt lgkmcnt(0)");
    __builtin_amdgcn_sched_barrier(0);
    __builtin_amdgcn_s_setprio(1);
    #pragma unroll
    for (int i = 0; i < 4; ++i)
      #pragma unroll
      for (int j = 0; j < 2; ++j) {
        acc[4 + i][2 + j] = MFMA16(afl[i][0], bf23[j][0], acc[4 + i][2 + j]);
        acc[4 + i][2 + j] = MFMA16(afl[i][1], bf23[j][1], acc[4 + i][2 + j]);
      }
    __builtin_amdgcn_s_setprio(0);
    BARRIER();

    // ---- phase 4: (m-hi x n01), bf01 in regs; stage A1,A3; retire 6 ------
    if (pf) {
      gld16(an + 1 * slabK, al + 1 * 8192);
      gld16(an + 3 * slabK, al + 3 * 8192);
      asm volatile("s_waitcnt vmcnt(2)" ::: "memory");  // B0-3,A0,A2(t+1) in
    }
    BARRIER();
    asm volatile("s_waitcnt lgkmcnt(0)");
    __builtin_amdgcn_sched_barrier(0);
    __builtin_amdgcn_s_setprio(1);
    #pragma unroll
    for (int i = 0; i < 4; ++i)
      #pragma unroll
      for (int j = 0; j < 2; ++j) {
        acc[4 + i][j] = MFMA16(afl[i][0], bf01[j][0], acc[4 + i][j]);
        acc[4 + i][j] = MFMA16(afl[i][1], bf01[j][1], acc[4 + i][j]);
      }
    __builtin_amdgcn_s_setprio(0);
    BARRIER();
  }

  // epilogue
  const int col = lane & 15, rq = (lane >> 4) * 4;
  if (mode == 1) {
    #pragma unroll
    for (int j = 0; j < 4; ++j) {
      const int gn = n0 + wn + j * 16 + col;
      const float bj = bias[gn];
      #pragma unroll
      for (int i = 0; i < 8; ++i)
        #pragma unroll
        for (int r = 0; r < 4; ++r)
          ((float*)C0)[(m0 + wm + i * 16 + rq + r) * (long)N + gn] =
              acc[i][j][r] + bj;
    }
  } else {
    // LDS-bounce vectorized bf16 epilogue. Wave-private 16x76 scratch in
    // As[0] (free after the final barrier of the main loop). Pitch 76:
    // write banks spread 4 distinct bases; read rows hit distinct banks.
    const bool qhalf = (n0 + 256 <= CDIM);
    __bf16* Cb = qhalf ? (__bf16*)C0 : (__bf16*)C1;
    const long cstride = qhalf ? CDIM : EDIM;
    const int ncol0 = qhalf ? (n0 + wn) : (n0 + wn - CDIM);
    __bf16* S = &As[0][0] + wave * (16 * 76);
    const int er = lane >> 2, ec = (lane & 3) * 8;
    #pragma unroll
    for (int i = 0; i < 8; ++i) {
      #pragma unroll
      for (int j = 0; j < 4; ++j)
        #pragma unroll
        for (int r = 0; r < 4; ++r)
          S[(rq + r) * 76 + j * 16 + col] = (__bf16)acc[i][j][r];
      asm volatile("s_waitcnt lgkmcnt(0)" ::: "memory");  // writes -> reads
      __builtin_amdgcn_sched_barrier(0);
      uint4 v0 = *(const uint4*)&S[er * 76 + ec];
      uint4 v1 = *(const uint4*)&S[er * 76 + ec + 32];
      __bf16* dst = Cb + (m0 + wm + i * 16 + er) * cstride + ncol0;
      *(uint4*)(dst + ec) = v0;
      *(uint4*)(dst + ec + 32) = v1;
      asm volatile("s_waitcnt lgkmcnt(0)" ::: "memory");  // reads -> next i
      __builtin_amdgcn_sched_barrier(0);
    }
  }
}

// ---------------------------------------------------------------------------
// 128x128 bf16 MFMA GEMM (m97 structure). Used for the proj GEMM (better
// grid packing: 256-thread blocks, 32 KB LDS -> ~2-3 blocks/CU).
// mode 1: fp32 + bias epilogue into C0 stride N.
// ---------------------------------------------------------------------------
__global__ __launch_bounds__(256) void gemm_glds_kernel(
    const __bf16* __restrict__ A, const __bf16* __restrict__ Bt,
    void* __restrict__ C0, void* __restrict__ C1,
    const float* __restrict__ bias,
    int M, int N, int K, int nxb, int mode) {
  __shared__ __bf16 As[128 * 32];
  __shared__ __bf16 Bs[128 * 32];
  const int tid = threadIdx.x;
  const int wave = tid >> 6, lane = tid & 63;

  const int flat = blockIdx.x;
  const int xcd = flat & 7, rem = flat >> 3;
  const int per = (M >> 7) >> 3;           // y-tiles per XCD
  const int yb = xcd * per + rem / nxb;
  const int xb = rem % nxb;
  const long m0 = (long)yb * 128;
  const int n0 = xb * 128;

  const int wm = (wave >> 1) * 64, wn = (wave & 1) * 64;

  const int srow = lane >> 2;
  const int gchunk = (lane & 3) ^ ((lane >> 3) & 3);
  const __bf16* Ag = A + (m0 + wave * 16 + srow) * (long)K + gchunk * 8;
  const __bf16* Bg = Bt + ((long)n0 + wave * 16 + srow) * (long)K + gchunk * 8;
  char* Al = (char*)As + wave * 16 * 64;   // + lane*16 applied by HW
  char* Bl = (char*)Bs + wave * 16 * 64;
  const long rowskip = 64 * (long)K;

  const int fr = lane & 15;
  const int csw = ((lane >> 4) ^ ((fr >> 1) & 3)) * 8;  // swizzled k-chunk

  floatx4 acc[4][4] = {};

  for (int k0 = 0; k0 < K; k0 += 32) {
    __syncthreads();
    gld16(Ag + k0, Al);
    gld16(Ag + k0 + rowskip, Al + 64 * 64);
    gld16(Bg + k0, Bl);
    gld16(Bg + k0 + rowskip, Bl + 64 * 64);
    __syncthreads();   // compiler drains vmcnt before s_barrier
    bf16x8 af[4], bfr[4];
    #pragma unroll
    for (int i = 0; i < 4; ++i)
      af[i] = *(const bf16x8*)&As[(wm + i * 16 + fr) * 32 + csw];
    #pragma unroll
    for (int j = 0; j < 4; ++j)
      bfr[j] = *(const bf16x8*)&Bs[(wn + j * 16 + fr) * 32 + csw];
    #pragma unroll
    for (int i = 0; i < 4; ++i)
      #pragma unroll
      for (int j = 0; j < 4; ++j)
        acc[i][j] = __builtin_amdgcn_mfma_f32_16x16x32_bf16(af[i], bfr[j], acc[i][j], 0, 0, 0);
  }

  const int col = lane & 15, rq = (lane >> 4) * 4;
  if (mode == 1) {
    #pragma unroll
    for (int i = 0; i < 4; ++i)
      #pragma unroll
      for (int j = 0; j < 4; ++j)
        #pragma unroll
        for (int r = 0; r < 4; ++r) {
          long gm = m0 + wm + i * 16 + rq + r;
          int gn = n0 + wn + j * 16 + col;
          ((float*)C0)[gm * N + gn] = acc[i][j][r] + bias[gn];
        }
  } else {
    if (n0 + 128 <= CDIM) {
      #pragma unroll
      for (int i = 0; i < 4; ++i)
        #pragma unroll
        for (int j = 0; j < 4; ++j)
          #pragma unroll
          for (int r = 0; r < 4; ++r) {
            long gm = m0 + wm + i * 16 + rq + r;
            int gn = n0 + wn + j * 16 + col;
            ((__bf16*)C0)[gm * CDIM + gn] = (__bf16)acc[i][j][r];
          }
    } else {
      #pragma unroll
      for (int i = 0; i < 4; ++i)
        #pragma unroll
        for (int j = 0; j < 4; ++j)
          #pragma unroll
          for (int r = 0; r < 4; ++r) {
            long gm = m0 + wm + i * 16 + rq + r;
            int gn = n0 + wn + j * 16 + col - CDIM;
            ((__bf16*)C1)[gm * EDIM + gn] = (__bf16)acc[i][j][r];
          }
    }
  }
}

// ---------------------------------------------------------------------------
// ktv partials with FUSED softmax over head_dim:
// ktv_part[split][b][h][d][e] = sum_{n in split} softmax(k[b,n,h,:])[d]*v[b,n,h,e]
// grid: (KSPLIT=8, NHEADS, NB), block 256 (4 waves, each 16 d-rows x 64 e-cols).
// Split-K = 8 -> 768 blocks = 3 waves/SIMD chip-wide (was 1.5: latency-bound).
// Softmax: the 8 lanes sharing a k-row (sn) hold its 64 values (8 each);
// 3-step shfl_xor max/sum within the 8-lane group, then normalize.
// ---------------------------------------------------------------------------
__global__ __launch_bounds__(256) void ktv_kernel(
    const __bf16* __restrict__ kv, float* __restrict__ ktv_part) {
  const int split = blockIdx.x, h = blockIdx.y, b = blockIdx.z;
  __shared__ __bf16 As[64 * 40];  // [d][n_local]
  __shared__ __bf16 Bs[64 * 40];  // [e][n_local]
  const int tid = threadIdx.x, wave = tid >> 6, lane = tid & 63;
  const int sn = tid >> 3;        // 0..31
  const int sc = (tid & 7) * 8;   // 0..56
  const int fr = lane & 15, fk = (lane >> 4) * 8;
  floatx4 acc[4] = {};
  const long rowbase = (long)b * NTOK * EDIM;
  const int span = NTOK / KSPLIT;  // 512

  for (int n0 = split * span; n0 < split * span + span; n0 += 32) {
    __syncthreads();
    const __bf16* krow = kv + rowbase + (long)(n0 + sn) * EDIM + h * HD + sc;
    const __bf16* vrow = krow + CDIM;
    uint4 ku = *(const uint4*)krow;
    uint4 vu = *(const uint4*)vrow;
    const __bf16* kh = (const __bf16*)&ku;
    const __bf16* vh = (const __bf16*)&vu;
    // fused softmax over this row's 64 k values (8 lanes x 8 elems)
    float kf[8];
    float mx = -1e30f;
    #pragma unroll
    for (int j = 0; j < 8; ++j) { kf[j] = (float)kh[j]; mx = fmaxf(mx, kf[j]); }
    #pragma unroll
    for (int m = 1; m < 8; m <<= 1) mx = fmaxf(mx, __shfl_xor(mx, m));
    float s = 0.f;
    #pragma unroll
    for (int j = 0; j < 8; ++j) { kf[j] = __expf(kf[j] - mx); s += kf[j]; }
    #pragma unroll
    for (int m = 1; m < 8; m <<= 1) s += __shfl_xor(s, m);
    const float inv = 1.f / s;
    #pragma unroll
    for (int j = 0; j < 8; ++j) {
      As[(sc + j) * 40 + sn] = (__bf16)(kf[j] * inv);
      Bs[(sc + j) * 40 + sn] = vh[j];
    }
    __syncthreads();
    bf16x8 af = *(const bf16x8*)&As[(wave * 16 + fr) * 40 + fk];
    #pragma unroll
    for (int j = 0; j < 4; ++j) {
      bf16x8 bf_ = *(const bf16x8*)&Bs[(j * 16 + fr) * 40 + fk];
      acc[j] = __builtin_amdgcn_mfma_f32_16x16x32_bf16(af, bf_, acc[j], 0, 0, 0);
    }
  }

  const int col = lane & 15, rq = (lane >> 4) * 4;
  long base = (((long)split * NB + b) * NHEADS + h) * (HD * HD);
  #pragma unroll
  for (int j = 0; j < 4; ++j)
    #pragma unroll
    for (int r = 0; r < 4; ++r)
      ktv_part[base + (wave * 16 + rq + r) * HD + j * 16 + col] = acc[j][r];
}

// ---------------------------------------------------------------------------
// Build expanded ektv TRANSPOSED (bf16, [b][H][e][d], H in [0,24)) from the
// KSPLIT partials, applying the head-expansion roll on the flattened
// (h*64+e) axis. Transposed layout keeps attn's B-stage fully coalesced.
// ---------------------------------------------------------------------------
__global__ __launch_bounds__(256) void ektv_kernel(
    const float* __restrict__ ktv_part, __bf16* __restrict__ ektv) {
  int idx = blockIdx.x * 256 + threadIdx.x;  // < 8*24*64*64 = 786432
  int e = idx & 63;
  int d = (idx >> 6) & 63;
  int H = (idx >> 12) % 24;
  int b = idx / 98304;
  int c = H * 64 + e;
  int cp = (c < CDIM) ? c : (c - CDIM + 32) % CDIM;
  int hs = cp >> 6, es = cp & 63;
  long o = (((long)b * NHEADS + hs) * HD + d) * HD + es;
  float s = 0.f;
  #pragma unroll
  for (int sp = 0; sp < KSPLIT; ++sp)
    s += ktv_part[(long)sp * (NB * NHEADS * HD * HD) + o];
  // transposed output: [b][H][e][d]
  long ob = ((long)(idx >> 12)) * (HD * HD) + (long)e * HD + d;
  ektv[ob] = (__bf16)s;
}

// ---------------------------------------------------------------------------
// attn: mid[b, n, H*64+e] = scale * sum_d eq[b,H,n,d] * ektv_t[b,H,e,d]
// eq columns for head H are q columns (qbase..qbase+63) mod 768.
// grid: (NTOK/128, 24, NB), block 256 (4 waves x 32 token rows).
// B-stage is a straight coalesced copy (ektv pre-transposed).
// ---------------------------------------------------------------------------
__global__ __launch_bounds__(256) void attn_kernel(
    const __bf16* __restrict__ q, const __bf16* __restrict__ ektv,
    __bf16* __restrict__ mid) {
  const int tt = blockIdx.x, H = blockIdx.y, b = blockIdx.z;
  __shared__ __bf16 As[128 * 72];  // [n_local][d]
  __shared__ __bf16 Bs[64 * 72];   // [e][d]
  const int tid = threadIdx.x, wave = tid >> 6, lane = tid & 63;
  const int qbase = (H < NHEADS) ? H * 64 : (H - NHEADS) * 64 + 32;
  const long n0 = (long)b * NTOK + tt * 128;

  {  // stage A (q slice, handling the circular roll per 8-wide chunk)
    int nl = tid >> 1, d0 = (tid & 1) * 32;
    const __bf16* qrow = q + (n0 + nl) * CDIM;
    #pragma unroll
    for (int cch = 0; cch < 4; ++cch) {
      int d = d0 + cch * 8;
      int c0 = qbase + d;
      if (c0 >= CDIM) c0 -= CDIM;
      *(uint4*)&As[nl * 72 + d] = *(const uint4*)(qrow + c0);
    }
  }
  {  // stage B: Bs[e][d] = ektv_t[b][H][e][d] (coalesced 16B copies)
    int e = tid >> 2, ch4 = (tid & 3) * 8;  // 2 chunks per thread
    const __bf16* src = ektv + ((long)b * 24 + H) * (HD * HD) + e * HD;
    *(uint4*)&Bs[e * 72 + ch4] = *(const uint4*)(src + ch4);
    *(uint4*)&Bs[e * 72 + ch4 + 32] = *(const uint4*)(src + ch4 + 32);
  }
  __syncthreads();

  floatx4 acc[2][4] = {};
  const int fr = lane & 15, fk = (lane >> 4) * 8;
  const int wm = wave * 32;
  #pragma unroll
  for (int kk = 0; kk < 64; kk += 32) {
    bf16x8 af0 = *(const bf16x8*)&As[(wm + fr) * 72 + kk + fk];
    bf16x8 af1 = *(const bf16x8*)&As[(wm + 16 + fr) * 72 + kk + fk];
    #pragma unroll
    for (int j = 0; j < 4; ++j) {
      bf16x8 bf_ = *(const bf16x8*)&Bs[(j * 16 + fr) * 72 + kk + fk];
      acc[0][j] = __builtin_amdgcn_mfma_f32_16x16x32_bf16(af0, bf_, acc[0][j], 0, 0, 0);
      acc[1][j] = __builtin_amdgcn_mfma_f32_16x16x32_bf16(af1, bf_, acc[1][j], 0, 0, 0);
    }
  }

  const int col = lane & 15, rq = (lane >> 4) * 4;
  const float scale = 0.125f;  // HEAD_DIM^-0.5
  #pragma unroll
  for (int i = 0; i < 2; ++i)
    #pragma unroll
    for (int j = 0; j < 4; ++j)
      #pragma unroll
      for (int r = 0; r < 4; ++r) {
        long n = n0 + wm + i * 16 + rq + r;
        mid[n * EDIM + H * 64 + j * 16 + col] = (__bf16)(acc[i][j][r] * scale);
      }
}

// ---------------------------------------------------------------------------
// LePE depthwise 3x3 conv, tiled through LDS, sliding-window register reuse.
// grid: (12 ch-groups of 64 q-channels, 16 y-groups of 4 rows, NB).
// ---------------------------------------------------------------------------
__global__ __launch_bounds__(256) void lepe_kernel(
    const __bf16* __restrict__ q, const float* __restrict__ w_lepe,
    const float* __restrict__ b_lepe, __bf16* __restrict__ mid) {
  __shared__ __bf16 smem[6 * 64 * 64];  // [row][x][ch], 48 KB
  const int g = blockIdx.x, yg = blockIdx.y, b = blockIdx.z;
  const int y0 = yg * 4;
  const int tid = threadIdx.x;

  #pragma unroll
  for (int k = 0; k < 12; ++k) {
    int v = tid + k * 256;            // 0..3071
    int r = v >> 9;                   // row in slab, 0..5
    int rem = v & 511;
    int x = rem >> 3;
    int chv = (rem & 7) * 8;
    int yy = y0 + r - 1;
    uint4 val = {0u, 0u, 0u, 0u};
    if (yy >= 0 && yy < 64)
      val = *(const uint4*)(q + ((long)(b * NTOK + yy * 64 + x)) * CDIM + g * 64 + chv);
    *(uint4*)&smem[r * 4096 + x * 64 + chv] = val;
  }
  __syncthreads();

  const int ch = tid & 63, xg = tid >> 6;
  const int cq = g * 64 + ch;                 // expanded channel (identity half)
  const int c2 = CDIM + ((cq + 736) % CDIM);  // rolled duplicate channel
  float w1[9], w2[9];
  #pragma unroll
  for (int j = 0; j < 9; ++j) {
    w1[j] = w_lepe[cq * 9 + j];
    w2[j] = w_lepe[c2 * 9 + j];
  }
  const float bias1 = b_lepe[cq], bias2 = b_lepe[c2];

  const int x0 = xg * 16;
  float cm[6], cc[6], cp[6];
  #pragma unroll
  for (int r = 0; r < 6; ++r) {
    cm[r] = (x0 > 0) ? (float)smem[r * 4096 + (x0 - 1) * 64 + ch] : 0.f;  // wave-uniform cond
    cc[r] = (float)smem[r * 4096 + x0 * 64 + ch];
  }
  #pragma unroll
  for (int i = 0; i < 16; ++i) {
    const int x = x0 + i;
    #pragma unroll
    for (int r = 0; r < 6; ++r)
      cp[r] = (x < 63) ? (float)smem[r * 4096 + (x + 1) * 64 + ch] : 0.f;  // wave-uniform
    #pragma unroll
    for (int ly = 0; ly < 4; ++ly) {
      float a1 = bias1, a2 = bias2;
      #pragma unroll
      for (int r = 0; r < 3; ++r) {
        const float vm = cm[ly + r], vc = cc[ly + r], vp = cp[ly + r];
        a1 += w1[r * 3 + 0] * vm + w1[r * 3 + 1] * vc + w1[r * 3 + 2] * vp;
        a2 += w2[r * 3 + 0] * vm + w2[r * 3 + 1] * vc + w2[r * 3 + 2] * vp;
      }
      long o = ((long)(b * NTOK + (y0 + ly) * 64 + x)) * EDIM;
      mid[o + cq] = (__bf16)((float)mid[o + cq] + a1);
      mid[o + c2] = (__bf16)((float)mid[o + c2] + a2);
    }
    #pragma unroll
    for (int r = 0; r < 6; ++r) { cm[r] = cc[r]; cc[r] = cp[r]; }
  }
}

// ---------------------------------------------------------------------------
// launch
// ---------------------------------------------------------------------------
extern "C" void kernel_launch(void* const* d_in, const int* in_sizes, int n_in,
                              void* d_out, int out_size, void* d_ws, size_t ws_size,
                              hipStream_t stream) {
  const float* x      = (const float*)d_in[0];
  const float* w_q    = (const float*)d_in[1];
  const float* w_kv   = (const float*)d_in[2];
  const float* w_proj = (const float*)d_in[3];
  const float* b_proj = (const float*)d_in[4];
  const float* w_lepe = (const float*)d_in[5];
  const float* b_lepe = (const float*)d_in[6];
  float* out = (float*)d_out;

  char* ws = (char*)d_ws;
  __bf16* Wt_qkv = (__bf16*)ws; ws += (long)(CDIM + EDIM) * CDIM * 2;  // 2304x768 (NxK)
  __bf16* Wt_p   = (__bf16*)ws; ws += (long)CDIM * EDIM * 2;           // 768x1536 (NxK)
  __bf16* xb     = (__bf16*)ws; ws += (long)TOTTOK * CDIM * 2;
  __bf16* qb     = (__bf16*)ws; ws += (long)TOTTOK * CDIM * 2;
  __bf16* kvb    = (__bf16*)ws; ws += (long)TOTTOK * EDIM * 2;         // later aliased as mid
  float*  ktv_part = (float*)ws; ws += (long)KSPLIT * NB * NHEADS * HD * HD * 4;
  __bf16* ektv   = (__bf16*)ws; ws += (long)NB * 24 * HD * HD * 2;
  __bf16* mid = kvb;  // alias: kv is dead once ektv is built

  // 1. x -> bf16
  f32_to_bf16_kernel<<<(TOTTOK * CDIM) / (256 * 4), 256, 0, stream>>>(
      x, xb, (long)TOTTOK * CDIM);
  // 2. weight transposes (K x N fp32 -> N x K bf16), q|kv concatenated
  transpose_w_kernel<<<dim3(CDIM / 32, CDIM / 32), 256, 0, stream>>>(
      w_q, Wt_qkv, CDIM, CDIM);
  transpose_w_kernel<<<dim3(EDIM / 32, CDIM / 32), 256, 0, stream>>>(
      w_kv, Wt_qkv + (long)CDIM * CDIM, CDIM, EDIM);
  transpose_w_kernel<<<dim3(CDIM / 32, EDIM / 32), 256, 0, stream>>>(
      w_proj, Wt_p, EDIM, CDIM);
  // 3. fused qkv = x @ [w_q | w_kv]  (256^2 8-phase, split epilogue -> qb, kvb)
  //    grid: (32768/256) y-tiles * 9 x-tiles = 1152 blocks
  gemm256_kernel<<<(TOTTOK / 256) * 9, 512, 0, stream>>>(
      xb, Wt_qkv, qb, kvb, nullptr, TOTTOK, CDIM + EDIM, CDIM, 9, 0);
  // 4. ktv partials (softmax fused into staging; split-K=8 over tokens)
  ktv_kernel<<<dim3(KSPLIT, NHEADS, NB), 256, 0, stream>>>(kvb, ktv_part);
  // 5. reduce partials + head-expand -> ektv (TRANSPOSED [b][H][e][d])
  ektv_kernel<<<(NB * 24 * HD * HD) / 256, 256, 0, stream>>>(ktv_part, ektv);
  // 6. attn -> mid (overwrites kv buffer)
  attn_kernel<<<dim3(NTOK / 128, 24, NB), 256, 0, stream>>>(qb, ektv, mid);
  // 7. mid += lepe (tiled, LDS-staged, sliding-window)
  lepe_kernel<<<dim3(12, 16, NB), 256, 0, stream>>>(qb, w_lepe, b_lepe, mid);
  // 8. out = mid @ w_proj + b_proj (128^2 m97 structure: better packing)
  //    grid: 256 y-tiles * 6 x-tiles = 1536 blocks
  gemm_glds_kernel<<<(TOTTOK / 128) * 6, 256, 0, stream>>>(
      mid, Wt_p, out, nullptr, b_proj, TOTTOK, CDIM, EDIM, 6, 1);
}

// Round 5
// 531.621 us; speedup vs baseline: 1.3426x; 1.1209x over previous
//
#include <hip/hip_runtime.h>

// ---------------------------------------------------------------------------
// Problem constants: B=8, N=4096 (64x64 image), DIM=768, HEADS=12, HEAD_DIM=64
// EXP=2 -> EDIM=1536, expanded heads = 24.
// ---------------------------------------------------------------------------
#define NB 8
#define NTOK 4096
#define CDIM 768
#define EDIM 1536
#define NHEADS 12
#define HD 64
#define TOTTOK (NB * NTOK)          // 32768
#define KSPLIT 8

typedef float floatx4 __attribute__((ext_vector_type(4)));
typedef __bf16 bf16x8 __attribute__((ext_vector_type(8)));

// async 16B global -> LDS (lane-contiguous LDS dest: wave base + lane*16)
__device__ __forceinline__ void gld16(const __bf16* g, void* l) {
  __builtin_amdgcn_global_load_lds(
      (const __attribute__((address_space(1))) unsigned int*)g,
      (__attribute__((address_space(3))) unsigned int*)l, 16, 0, 0);
}

#define MFMA16(a, b, c) __builtin_amdgcn_mfma_f32_16x16x32_bf16(a, b, c, 0, 0, 0)
#define FENCE() asm volatile("" ::: "memory")
#define BARRIER() do { FENCE(); __builtin_amdgcn_s_barrier(); FENCE(); } while (0)

// ---------------------------------------------------------------------------
// fp32 -> bf16 elementwise convert (x)
// ---------------------------------------------------------------------------
__global__ __launch_bounds__(256) void f32_to_bf16_kernel(
    const float* __restrict__ in, __bf16* __restrict__ out, long n) {
  long i = ((long)blockIdx.x * 256 + threadIdx.x) * 4;
  if (i >= n) return;
  float4 f = *(const float4*)(in + i);
  alignas(8) __bf16 h[4];
  h[0] = (__bf16)f.x; h[1] = (__bf16)f.y; h[2] = (__bf16)f.z; h[3] = (__bf16)f.w;
  *(unsigned long long*)(out + i) = *(const unsigned long long*)h;
}

// ---------------------------------------------------------------------------
// W (K x N fp32, row-major) -> Wt (N x K bf16, row-major)
// grid: (N/32, K/32), block 256
// ---------------------------------------------------------------------------
__global__ __launch_bounds__(256) void transpose_w_kernel(
    const float* __restrict__ W, __bf16* __restrict__ Wt, int K, int N) {
  __shared__ float tile[32][33];
  int nb = blockIdx.x * 32, kb = blockIdx.y * 32;
  int tx = threadIdx.x & 31, ty = threadIdx.x >> 5;  // ty 0..7
  #pragma unroll
  for (int i = ty; i < 32; i += 8)
    tile[i][tx] = W[(long)(kb + i) * N + nb + tx];
  __syncthreads();
  #pragma unroll
  for (int i = ty; i < 32; i += 8)
    Wt[(long)(nb + i) * K + kb + tx] = (__bf16)tile[tx][i];
}

// ---------------------------------------------------------------------------
// 256x256 8-phase bf16 MFMA GEMM (T2+T3+T4+T5). Used for the qkv GEMM.
// C(MxN) = A(MxK) @ Bt(NxK)^T. BK=64, 512 threads = 8 waves (2M x 4N),
// per-wave output 128x64 (acc[8][4] 16x16 frags), LDS 128 KiB (2-deep dbuf).
//
// Staging: per K-tile, 8 slices of 64 rows x 64 cols (A0..A3, B0..B3); each
// slice = 1 global_load_lds_dwordx4 per wave. LDS dest linear; chunk XOR
// swizzle (stored chunk s at row r holds logical s^(r&7)) applied by
// pre-swizzling the per-lane GLOBAL source (both-sides swizzle, rule #21).
//
// Schedule (tile t computes buf[t&1], stages t+1 -> buf[~t&1]).
// R2 lesson: SPREAD the 8 staging loads 2-per-phase (burst-issue at ph1
// regressed 164->192 us). bf01/bf23 retained in regs (ph4 has no ds_reads).
//   ph1: read af-lo(8)+bf01(4) | stage B0,B1(t+1)
//   ph2: read bf23(4)          | stage B2,B3(t+1), vmcnt(4) [retire A1,A3(t)]
//   ph3: read af-hi(8)         | stage A0,A2(t+1)
//   ph4: no reads              | stage A1,A3(t+1), vmcnt(2) [retire B0-3,A0,A2]
// Invariant entering each tile: only A1,A3(t) in flight. vmcnt never 0 in
// main loop; last tile drains at ph2.
//
// R4 (verified): mode-0 epilogue via wave-private LDS bounce -> WRITE_SIZE
// dropped to exactly logical (217->147 MB), dur 168->152 us.
//
// Block swizzle: flat&7 = XCD owns a contiguous y-strip; needs (M/256)%8==0.
// mode 0: split bf16 epilogue (cols<768 -> C0 stride 768; else C1 stride 1536)
// mode 1: fp32 + bias epilogue into C0 stride N.
// ---------------------------------------------------------------------------
__global__ __launch_bounds__(512, 2) void gemm256_kernel(
    const __bf16* __restrict__ A, const __bf16* __restrict__ Bt,
    void* __restrict__ C0, void* __restrict__ C1,
    const float* __restrict__ bias,
    int M, int N, int K, int nxb, int mode) {
  __shared__ __bf16 As[2][256 * 64];   // 64 KB
  __shared__ __bf16 Bs[2][256 * 64];   // 64 KB
  const int tid = threadIdx.x;
  const int wave = tid >> 6, lane = tid & 63;

  const int flat = blockIdx.x;
  const int xcd = flat & 7, rem = flat >> 3;
  const int per = (M >> 8) >> 3;           // y-tiles per XCD
  const int yb = xcd * per + rem / nxb;
  const int xb = rem % nxb;
  const long m0 = (long)yb * 256;
  const int n0 = xb * 256;

  const int wm = (wave >> 2) * 128;        // M-half of this wave
  const int wn = (wave & 3) * 64;          // N-quarter of this wave

  // staging: wave covers rows [wave*8, wave*8+8) of each 64-row slice.
  const int srow = lane >> 3;              // 0..7 == row&7
  const int gchunk = (lane & 7) ^ srow;
  const __bf16* Ag = A + (m0 + wave * 8 + srow) * (long)K + gchunk * 8;
  const __bf16* Bg = Bt + ((long)n0 + wave * 8 + srow) * (long)K + gchunk * 8;
  const long slabK = 64 * (long)K;         // global elems between slices

  const int fr = lane & 15, qh = lane >> 4;
  const int c0 = ((qh ^ (fr & 7)) << 3);        // stored-chunk offset, kk=0
  const int c1 = (((qh + 4) ^ (fr & 7)) << 3);  // stored-chunk offset, kk=1

  floatx4 acc[8][4] = {};
  bf16x8 afl[4][2], bf01[2][2], bf23[2][2];
  const int nt = K >> 6;

  // prologue: stage tile 0; order B0..B3, A0, A2, A1, A3 (A1,A3 newest)
  {
    char* al = (char*)&As[0][0] + wave * 1024;
    char* bl = (char*)&Bs[0][0] + wave * 1024;
    gld16(Bg + 0 * slabK, bl + 0 * 8192);
    gld16(Bg + 1 * slabK, bl + 1 * 8192);
    gld16(Bg + 2 * slabK, bl + 2 * 8192);
    gld16(Bg + 3 * slabK, bl + 3 * 8192);
    gld16(Ag + 0 * slabK, al + 0 * 8192);
    gld16(Ag + 2 * slabK, al + 2 * 8192);
    gld16(Ag + 1 * slabK, al + 1 * 8192);
    gld16(Ag + 3 * slabK, al + 3 * 8192);
  }
  asm volatile("s_waitcnt vmcnt(2)" ::: "memory");  // A1,A3 stay in flight
  BARRIER();

  for (int t = 0; t < nt; ++t) {
    const int cur = t & 1;
    const bool pf = (t + 1 < nt);
    const __bf16* Ac = &As[cur][0];
    const __bf16* Bc = &Bs[cur][0];
    const __bf16* an = Ag + (t + 1) * 64;
    const __bf16* bn = Bg + (t + 1) * 64;
    char* al = (char*)&As[cur ^ 1][0] + wave * 1024;
    char* bl = (char*)&Bs[cur ^ 1][0] + wave * 1024;

    // ---- phase 1: (m-lo x n01); stage B0,B1 ------------------------------
    #pragma unroll
    for (int i = 0; i < 4; ++i) {
      const __bf16* p = &Ac[(wm + i * 16 + fr) * 64];
      afl[i][0] = *(const bf16x8*)(p + c0);
      afl[i][1] = *(const bf16x8*)(p + c1);
    }
    #pragma unroll
    for (int j = 0; j < 2; ++j) {
      const __bf16* p = &Bc[(wn + j * 16 + fr) * 64];
      bf01[j][0] = *(const bf16x8*)(p + c0);
      bf01[j][1] = *(const bf16x8*)(p + c1);
    }
    if (pf) { gld16(bn + 0 * slabK, bl + 0 * 8192);
              gld16(bn + 1 * slabK, bl + 1 * 8192); }
    BARRIER();
    asm volatile("s_waitcnt lgkmcnt(0)");
    __builtin_amdgcn_sched_barrier(0);
    __builtin_amdgcn_s_setprio(1);
    #pragma unroll
    for (int i = 0; i < 4; ++i)
      #pragma unroll
      for (int j = 0; j < 2; ++j) {
        acc[i][j] = MFMA16(afl[i][0], bf01[j][0], acc[i][j]);
        acc[i][j] = MFMA16(afl[i][1], bf01[j][1], acc[i][j]);
      }
    __builtin_amdgcn_s_setprio(0);
    BARRIER();

    // ---- phase 2: (m-lo x n23); stage B2,B3; retire A1,A3(t) -------------
    #pragma unroll
    for (int j = 0; j < 2; ++j) {
      const __bf16* p = &Bc[(wn + (2 + j) * 16 + fr) * 64];
      bf23[j][0] = *(const bf16x8*)(p + c0);
      bf23[j][1] = *(const bf16x8*)(p + c1);
    }
    if (pf) {
      gld16(bn + 2 * slabK, bl + 2 * 8192);
      gld16(bn + 3 * slabK, bl + 3 * 8192);
      asm volatile("s_waitcnt vmcnt(4)" ::: "memory");
    } else {
      asm volatile("s_waitcnt vmcnt(0)" ::: "memory");  // last tile: drain
    }
    BARRIER();
    asm volatile("s_waitcnt lgkmcnt(0)");
    __builtin_amdgcn_sched_barrier(0);
    __builtin_amdgcn_s_setprio(1);
    #pragma unroll
    for (int i = 0; i < 4; ++i)
      #pragma unroll
      for (int j = 0; j < 2; ++j) {
        acc[i][2 + j] = MFMA16(afl[i][0], bf23[j][0], acc[i][2 + j]);
        acc[i][2 + j] = MFMA16(afl[i][1], bf23[j][1], acc[i][2 + j]);
      }
    __builtin_amdgcn_s_setprio(0);
    BARRIER();

    // ---- phase 3: (m-hi x n23), bf23 in regs; stage A0,A2 ----------------
    #pragma unroll
    for (int i = 0; i < 4; ++i) {
      const __bf16* p = &Ac[(wm + (4 + i) * 16 + fr) * 64];
      afl[i][0] = *(const bf16x8*)(p + c0);
      afl[i][1] = *(const bf16x8*)(p + c1);
    }
    if (pf) { gld16(an + 0 * slabK, al + 0 * 8192);
              gld16(an + 2 * slabK, al + 2 * 8192); }
    BARRIER();
    asm volatile("s_waitcnt lgkmcnt(0)");
    __builtin_amdgcn_sched_barrier(0);
    __builtin_amdgcn_s_setprio(1);
    #pragma unroll
    for (int i = 0; i < 4; ++i)
      #pragma unroll
      for (int j = 0; j < 2; ++j) {
        acc[4 + i][2 + j] = MFMA16(afl[i][0], bf23[j][0], acc[4 + i][2 + j]);
        acc[4 + i][2 + j] = MFMA16(afl[i][1], bf23[j][1], acc[4 + i][2 + j]);
      }
    __builtin_amdgcn_s_setprio(0);
    BARRIER();

    // ---- phase 4: (m-hi x n01), bf01 in regs; stage A1,A3; retire 6 ------
    if (pf) {
      gld16(an + 1 * slabK, al + 1 * 8192);
      gld16(an + 3 * slabK, al + 3 * 8192);
      asm volatile("s_waitcnt vmcnt(2)" ::: "memory");  // B0-3,A0,A2(t+1) in
    }
    BARRIER();
    asm volatile("s_waitcnt lgkmcnt(0)");
    __builtin_amdgcn_sched_barrier(0);
    __builtin_amdgcn_s_setprio(1);
    #pragma unroll
    for (int i = 0; i < 4; ++i)
      #pragma unroll
      for (int j = 0; j < 2; ++j) {
        acc[4 + i][j] = MFMA16(afl[i][0], bf01[j][0], acc[4 + i][j]);
        acc[4 + i][j] = MFMA16(afl[i][1], bf01[j][1], acc[4 + i][j]);
      }
    __builtin_amdgcn_s_setprio(0);
    BARRIER();
  }

  // epilogue
  const int col = lane & 15, rq = (lane >> 4) * 4;
  if (mode == 1) {
    #pragma unroll
    for (int j = 0; j < 4; ++j) {
      const int gn = n0 + wn + j * 16 + col;
      const float bj = bias[gn];
      #pragma unroll
      for (int i = 0; i < 8; ++i)
        #pragma unroll
        for (int r = 0; r < 4; ++r)
          ((float*)C0)[(m0 + wm + i * 16 + rq + r) * (long)N + gn] =
              acc[i][j][r] + bj;
    }
  } else {
    // LDS-bounce vectorized bf16 epilogue (R4, verified).
    const bool qhalf = (n0 + 256 <= CDIM);
    __bf16* Cb = qhalf ? (__bf16*)C0 : (__bf16*)C1;
    const long cstride = qhalf ? CDIM : EDIM;
    const int ncol0 = qhalf ? (n0 + wn) : (n0 + wn - CDIM);
    __bf16* S = &As[0][0] + wave * (16 * 76);
    const int er = lane >> 2, ec = (lane & 3) * 8;
    #pragma unroll
    for (int i = 0; i < 8; ++i) {
      #pragma unroll
      for (int j = 0; j < 4; ++j)
        #pragma unroll
        for (int r = 0; r < 4; ++r)
          S[(rq + r) * 76 + j * 16 + col] = (__bf16)acc[i][j][r];
      asm volatile("s_waitcnt lgkmcnt(0)" ::: "memory");  // writes -> reads
      __builtin_amdgcn_sched_barrier(0);
      uint4 v0 = *(const uint4*)&S[er * 76 + ec];
      uint4 v1 = *(const uint4*)&S[er * 76 + ec + 32];
      __bf16* dst = Cb + (m0 + wm + i * 16 + er) * cstride + ncol0;
      *(uint4*)(dst + ec) = v0;
      *(uint4*)(dst + ec + 32) = v1;
      asm volatile("s_waitcnt lgkmcnt(0)" ::: "memory");  // reads -> next i
      __builtin_amdgcn_sched_barrier(0);
    }
  }
}

// ---------------------------------------------------------------------------
// 128x128 bf16 MFMA GEMM (m97 structure). Used for the proj GEMM.
// mode 1: fp32 + bias epilogue into C0 stride N.
// ---------------------------------------------------------------------------
__global__ __launch_bounds__(256) void gemm_glds_kernel(
    const __bf16* __restrict__ A, const __bf16* __restrict__ Bt,
    void* __restrict__ C0, void* __restrict__ C1,
    const float* __restrict__ bias,
    int M, int N, int K, int nxb, int mode) {
  __shared__ __bf16 As[128 * 32];
  __shared__ __bf16 Bs[128 * 32];
  const int tid = threadIdx.x;
  const int wave = tid >> 6, lane = tid & 63;

  const int flat = blockIdx.x;
  const int xcd = flat & 7, rem = flat >> 3;
  const int per = (M >> 7) >> 3;           // y-tiles per XCD
  const int yb = xcd * per + rem / nxb;
  const int xb = rem % nxb;
  const long m0 = (long)yb * 128;
  const int n0 = xb * 128;

  const int wm = (wave >> 1) * 64, wn = (wave & 1) * 64;

  const int srow = lane >> 2;
  const int gchunk = (lane & 3) ^ ((lane >> 3) & 3);
  const __bf16* Ag = A + (m0 + wave * 16 + srow) * (long)K + gchunk * 8;
  const __bf16* Bg = Bt + ((long)n0 + wave * 16 + srow) * (long)K + gchunk * 8;
  char* Al = (char*)As + wave * 16 * 64;   // + lane*16 applied by HW
  char* Bl = (char*)Bs + wave * 16 * 64;
  const long rowskip = 64 * (long)K;

  const int fr = lane & 15;
  const int csw = ((lane >> 4) ^ ((fr >> 1) & 3)) * 8;  // swizzled k-chunk

  floatx4 acc[4][4] = {};

  for (int k0 = 0; k0 < K; k0 += 32) {
    __syncthreads();
    gld16(Ag + k0, Al);
    gld16(Ag + k0 + rowskip, Al + 64 * 64);
    gld16(Bg + k0, Bl);
    gld16(Bg + k0 + rowskip, Bl + 64 * 64);
    __syncthreads();   // compiler drains vmcnt before s_barrier
    bf16x8 af[4], bfr[4];
    #pragma unroll
    for (int i = 0; i < 4; ++i)
      af[i] = *(const bf16x8*)&As[(wm + i * 16 + fr) * 32 + csw];
    #pragma unroll
    for (int j = 0; j < 4; ++j)
      bfr[j] = *(const bf16x8*)&Bs[(wn + j * 16 + fr) * 32 + csw];
    #pragma unroll
    for (int i = 0; i < 4; ++i)
      #pragma unroll
      for (int j = 0; j < 4; ++j)
        acc[i][j] = __builtin_amdgcn_mfma_f32_16x16x32_bf16(af[i], bfr[j], acc[i][j], 0, 0, 0);
  }

  const int col = lane & 15, rq = (lane >> 4) * 4;
  if (mode == 1) {
    #pragma unroll
    for (int i = 0; i < 4; ++i)
      #pragma unroll
      for (int j = 0; j < 4; ++j)
        #pragma unroll
        for (int r = 0; r < 4; ++r) {
          long gm = m0 + wm + i * 16 + rq + r;
          int gn = n0 + wn + j * 16 + col;
          ((float*)C0)[gm * N + gn] = acc[i][j][r] + bias[gn];
        }
  } else {
    if (n0 + 128 <= CDIM) {
      #pragma unroll
      for (int i = 0; i < 4; ++i)
        #pragma unroll
        for (int j = 0; j < 4; ++j)
          #pragma unroll
          for (int r = 0; r < 4; ++r) {
            long gm = m0 + wm + i * 16 + rq + r;
            int gn = n0 + wn + j * 16 + col;
            ((__bf16*)C0)[gm * CDIM + gn] = (__bf16)acc[i][j][r];
          }
    } else {
      #pragma unroll
      for (int i = 0; i < 4; ++i)
        #pragma unroll
        for (int j = 0; j < 4; ++j)
          #pragma unroll
          for (int r = 0; r < 4; ++r) {
            long gm = m0 + wm + i * 16 + rq + r;
            int gn = n0 + wn + j * 16 + col - CDIM;
            ((__bf16*)C1)[gm * EDIM + gn] = (__bf16)acc[i][j][r];
          }
    }
  }
}

// ---------------------------------------------------------------------------
// ktv partials with FUSED softmax over head_dim:
// ktv_part[split][b][h][d][e] = sum_{n in split} softmax(k[b,n,h,:])[d]*v[b,n,h,e]
// grid: (KSPLIT=8, NHEADS, NB), block 256 (4 waves, each 16 d-rows x 64 e-cols).
// ---------------------------------------------------------------------------
__global__ __launch_bounds__(256) void ktv_kernel(
    const __bf16* __restrict__ kv, float* __restrict__ ktv_part) {
  const int split = blockIdx.x, h = blockIdx.y, b = blockIdx.z;
  __shared__ __bf16 As[64 * 40];  // [d][n_local]
  __shared__ __bf16 Bs[64 * 40];  // [e][n_local]
  const int tid = threadIdx.x, wave = tid >> 6, lane = tid & 63;
  const int sn = tid >> 3;        // 0..31
  const int sc = (tid & 7) * 8;   // 0..56
  const int fr = lane & 15, fk = (lane >> 4) * 8;
  floatx4 acc[4] = {};
  const long rowbase = (long)b * NTOK * EDIM;
  const int span = NTOK / KSPLIT;  // 512

  for (int n0 = split * span; n0 < split * span + span; n0 += 32) {
    __syncthreads();
    const __bf16* krow = kv + rowbase + (long)(n0 + sn) * EDIM + h * HD + sc;
    const __bf16* vrow = krow + CDIM;
    uint4 ku = *(const uint4*)krow;
    uint4 vu = *(const uint4*)vrow;
    const __bf16* kh = (const __bf16*)&ku;
    const __bf16* vh = (const __bf16*)&vu;
    // fused softmax over this row's 64 k values (8 lanes x 8 elems)
    float kf[8];
    float mx = -1e30f;
    #pragma unroll
    for (int j = 0; j < 8; ++j) { kf[j] = (float)kh[j]; mx = fmaxf(mx, kf[j]); }
    #pragma unroll
    for (int m = 1; m < 8; m <<= 1) mx = fmaxf(mx, __shfl_xor(mx, m));
    float s = 0.f;
    #pragma unroll
    for (int j = 0; j < 8; ++j) { kf[j] = __expf(kf[j] - mx); s += kf[j]; }
    #pragma unroll
    for (int m = 1; m < 8; m <<= 1) s += __shfl_xor(s, m);
    const float inv = 1.f / s;
    #pragma unroll
    for (int j = 0; j < 8; ++j) {
      As[(sc + j) * 40 + sn] = (__bf16)(kf[j] * inv);
      Bs[(sc + j) * 40 + sn] = vh[j];
    }
    __syncthreads();
    bf16x8 af = *(const bf16x8*)&As[(wave * 16 + fr) * 40 + fk];
    #pragma unroll
    for (int j = 0; j < 4; ++j) {
      bf16x8 bf_ = *(const bf16x8*)&Bs[(j * 16 + fr) * 40 + fk];
      acc[j] = __builtin_amdgcn_mfma_f32_16x16x32_bf16(af, bf_, acc[j], 0, 0, 0);
    }
  }

  const int col = lane & 15, rq = (lane >> 4) * 4;
  long base = (((long)split * NB + b) * NHEADS + h) * (HD * HD);
  #pragma unroll
  for (int j = 0; j < 4; ++j)
    #pragma unroll
    for (int r = 0; r < 4; ++r)
      ktv_part[base + (wave * 16 + rq + r) * HD + j * 16 + col] = acc[j][r];
}

// ---------------------------------------------------------------------------
// Build expanded ektv TRANSPOSED (bf16, [b][H][e][d], H in [0,24)) from the
// KSPLIT partials, applying the head-expansion roll on the flattened
// (h*64+e) axis. Transposed layout keeps attn's B-stage fully coalesced.
// ---------------------------------------------------------------------------
__global__ __launch_bounds__(256) void ektv_kernel(
    const float* __restrict__ ktv_part, __bf16* __restrict__ ektv) {
  int idx = blockIdx.x * 256 + threadIdx.x;  // < 8*24*64*64 = 786432
  int e = idx & 63;
  int d = (idx >> 6) & 63;
  int H = (idx >> 12) % 24;
  int b = idx / 98304;
  int c = H * 64 + e;
  int cp = (c < CDIM) ? c : (c - CDIM + 32) % CDIM;
  int hs = cp >> 6, es = cp & 63;
  long o = (((long)b * NHEADS + hs) * HD + d) * HD + es;
  float s = 0.f;
  #pragma unroll
  for (int sp = 0; sp < KSPLIT; ++sp)
    s += ktv_part[(long)sp * (NB * NHEADS * HD * HD) + o];
  // transposed output: [b][H][e][d]
  long ob = ((long)(idx >> 12)) * (HD * HD) + (long)e * HD + d;
  ektv[ob] = (__bf16)s;
}

// ---------------------------------------------------------------------------
// FUSED attn + LePE:
// mid[b, n, H*64+e] = scale * sum_d eq[b,H,n,d] * ektv_t[b,H,e,d]
//                   + (dwconv3x3(eq_spatial)[b, H*64+e, y, x] + b_lepe)
// Key identity: conv input channel for expanded channel c=H*64+e is q column
// (qbase+e)%768 -- exactly the columns this block stages for its A matrix.
// So stage 4 image rows (y0-1..y0+2, 256 tokens) instead of 2, run the MFMA
// on the middle 128, and add the 3x3 conv in the epilogue from LDS
// (3-row x 6-col register window per 4 horizontally-adjacent outputs).
// grid: (NTOK/128 = 32 tt (2 image rows each), 24 H, NB), block 256.
// ---------------------------------------------------------------------------
__global__ __launch_bounds__(256) void attn_lepe_kernel(
    const __bf16* __restrict__ q, const __bf16* __restrict__ ektv,
    const float* __restrict__ w_lepe, const float* __restrict__ b_lepe,
    __bf16* __restrict__ mid) {
  const int tt = blockIdx.x, H = blockIdx.y, b = blockIdx.z;
  __shared__ __bf16 Qs[256 * 72];  // [tok: img rows y0-1..y0+2][d], 36 KB
  __shared__ __bf16 Bs[64 * 72];   // [e][d], 9 KB
  const int tid = threadIdx.x, wave = tid >> 6, lane = tid & 63;
  const int qbase = (H < NHEADS) ? H * 64 : (H - NHEADS) * 64 + 32;
  const int y0 = tt * 2;
  const long n0 = (long)b * NTOK + tt * 128;

  {  // stage Qs: 4 image rows x 64 rolled q columns (halo rows zero-filled)
    int nl = tid >> 1, d0 = (tid & 1) * 32;
    #pragma unroll
    for (int rep = 0; rep < 2; ++rep) {
      int tok = rep * 128 + nl;
      int iy = y0 - 1 + (tok >> 6);
      bool valid = (iy >= 0 && iy < 64);      // wave-uniform
      int iyc = valid ? iy : 0;
      const __bf16* qrow = q + ((long)b * NTOK + iyc * 64 + (tok & 63)) * CDIM;
      #pragma unroll
      for (int cch = 0; cch < 4; ++cch) {
        int d = d0 + cch * 8;
        int c0 = qbase + d;
        if (c0 >= CDIM) c0 -= CDIM;
        uint4 v = {0u, 0u, 0u, 0u};
        if (valid) v = *(const uint4*)(qrow + c0);
        *(uint4*)&Qs[tok * 72 + d] = v;
      }
    }
  }
  {  // stage B: Bs[e][d] = ektv_t[b][H][e][d] (coalesced 16B copies)
    int e = tid >> 2, ch4 = (tid & 3) * 8;
    const __bf16* src = ektv + ((long)b * 24 + H) * (HD * HD) + e * HD;
    *(uint4*)&Bs[e * 72 + ch4] = *(const uint4*)(src + ch4);
    *(uint4*)&Bs[e * 72 + ch4 + 32] = *(const uint4*)(src + ch4 + 32);
  }
  __syncthreads();

  floatx4 acc[2][4] = {};
  const int fr = lane & 15, fk = (lane >> 4) * 8;
  const int wm = wave * 32;
  #pragma unroll
  for (int kk = 0; kk < 64; kk += 32) {
    bf16x8 af0 = *(const bf16x8*)&Qs[(64 + wm + fr) * 72 + kk + fk];
    bf16x8 af1 = *(const bf16x8*)&Qs[(64 + wm + 16 + fr) * 72 + kk + fk];
    #pragma unroll
    for (int j = 0; j < 4; ++j) {
      bf16x8 bf_ = *(const bf16x8*)&Bs[(j * 16 + fr) * 72 + kk + fk];
      acc[0][j] = __builtin_amdgcn_mfma_f32_16x16x32_bf16(af0, bf_, acc[0][j], 0, 0, 0);
      acc[1][j] = __builtin_amdgcn_mfma_f32_16x16x32_bf16(af1, bf_, acc[1][j], 0, 0, 0);
    }
  }

  // epilogue: per thread 2x4x4 outputs; conv weights for its 4 channels
  const int col = lane & 15, rq4 = (lane >> 4) * 4;
  const float scale = 0.125f;  // HEAD_DIM^-0.5
  float wf[4][9], bf[4];
  #pragma unroll
  for (int j = 0; j < 4; ++j) {
    int c = H * 64 + j * 16 + col;
    #pragma unroll
    for (int t = 0; t < 9; ++t) wf[j][t] = w_lepe[c * 9 + t];
    bf[j] = b_lepe[c];
  }

  #pragma unroll
  for (int i = 0; i < 2; ++i) {
    const int ln0 = wm + i * 16 + rq4;       // first of 4 consecutive tokens
    const int ly = ln0 >> 6, lx0 = ln0 & 63; // same image row for r=0..3
    #pragma unroll
    for (int j = 0; j < 4; ++j) {
      const int d = j * 16 + col;
      // 3-row x 6-col window around columns lx0-1 .. lx0+4
      float win[3][6];
      #pragma unroll
      for (int dr = 0; dr < 3; ++dr) {
        const int rowb = (ly + dr) * 64;     // Qs tok base for img row y+dr-1
        #pragma unroll
        for (int s = 0; s < 6; ++s) {
          int xx = lx0 - 1 + s;
          win[dr][s] = (xx >= 0 && xx < 64)
                           ? (float)Qs[(rowb + xx) * 72 + d] : 0.f;
        }
      }
      #pragma unroll
      for (int r = 0; r < 4; ++r) {
        float conv = bf[j];
        #pragma unroll
        for (int dr = 0; dr < 3; ++dr)
          conv += wf[j][dr * 3 + 0] * win[dr][r] +
                  wf[j][dr * 3 + 1] * win[dr][r + 1] +
                  wf[j][dr * 3 + 2] * win[dr][r + 2];
        long n = n0 + ln0 + r;
        mid[n * EDIM + H * 64 + d] = (__bf16)(acc[i][j][r] * scale + conv);
      }
    }
  }
}

// ---------------------------------------------------------------------------
// launch
// ---------------------------------------------------------------------------
extern "C" void kernel_launch(void* const* d_in, const int* in_sizes, int n_in,
                              void* d_out, int out_size, void* d_ws, size_t ws_size,
                              hipStream_t stream) {
  const float* x      = (const float*)d_in[0];
  const float* w_q    = (const float*)d_in[1];
  const float* w_kv   = (const float*)d_in[2];
  const float* w_proj = (const float*)d_in[3];
  const float* b_proj = (const float*)d_in[4];
  const float* w_lepe = (const float*)d_in[5];
  const float* b_lepe = (const float*)d_in[6];
  float* out = (float*)d_out;

  char* ws = (char*)d_ws;
  __bf16* Wt_qkv = (__bf16*)ws; ws += (long)(CDIM + EDIM) * CDIM * 2;  // 2304x768 (NxK)
  __bf16* Wt_p   = (__bf16*)ws; ws += (long)CDIM * EDIM * 2;           // 768x1536 (NxK)
  __bf16* xb     = (__bf16*)ws; ws += (long)TOTTOK * CDIM * 2;
  __bf16* qb     = (__bf16*)ws; ws += (long)TOTTOK * CDIM * 2;
  __bf16* kvb    = (__bf16*)ws; ws += (long)TOTTOK * EDIM * 2;         // later aliased as mid
  float*  ktv_part = (float*)ws; ws += (long)KSPLIT * NB * NHEADS * HD * HD * 4;
  __bf16* ektv   = (__bf16*)ws; ws += (long)NB * 24 * HD * HD * 2;
  __bf16* mid = kvb;  // alias: kv is dead once ektv is built

  // 1. x -> bf16
  f32_to_bf16_kernel<<<(TOTTOK * CDIM) / (256 * 4), 256, 0, stream>>>(
      x, xb, (long)TOTTOK * CDIM);
  // 2. weight transposes (K x N fp32 -> N x K bf16), q|kv concatenated
  transpose_w_kernel<<<dim3(CDIM / 32, CDIM / 32), 256, 0, stream>>>(
      w_q, Wt_qkv, CDIM, CDIM);
  transpose_w_kernel<<<dim3(EDIM / 32, CDIM / 32), 256, 0, stream>>>(
      w_kv, Wt_qkv + (long)CDIM * CDIM, CDIM, EDIM);
  transpose_w_kernel<<<dim3(CDIM / 32, EDIM / 32), 256, 0, stream>>>(
      w_proj, Wt_p, EDIM, CDIM);
  // 3. fused qkv = x @ [w_q | w_kv]  (256^2 8-phase, split epilogue -> qb, kvb)
  gemm256_kernel<<<(TOTTOK / 256) * 9, 512, 0, stream>>>(
      xb, Wt_qkv, qb, kvb, nullptr, TOTTOK, CDIM + EDIM, CDIM, 9, 0);
  // 4. ktv partials (softmax fused into staging; split-K=8 over tokens)
  ktv_kernel<<<dim3(KSPLIT, NHEADS, NB), 256, 0, stream>>>(kvb, ktv_part);
  // 5. reduce partials + head-expand -> ektv (TRANSPOSED [b][H][e][d])
  ektv_kernel<<<(NB * 24 * HD * HD) / 256, 256, 0, stream>>>(ktv_part, ektv);
  // 6. attn + LePE fused -> mid (overwrites kv buffer); lepe kernel deleted
  attn_lepe_kernel<<<dim3(NTOK / 128, 24, NB), 256, 0, stream>>>(
      qb, ektv, w_lepe, b_lepe, mid);
  // 7. out = mid @ w_proj + b_proj (128^2 m97 structure)
  gemm_glds_kernel<<<(TOTTOK / 128) * 6, 256, 0, stream>>>(
      mid, Wt_p, out, nullptr, b_proj, TOTTOK, CDIM, EDIM, 6, 1);
}